// Round 8
// baseline (594.048 us; speedup 1.0000x reference)
//
#include <hip/hip_runtime.h>
#include <hip/hip_bf16.h>

#define N_NODES 50000
#define N_EDGES 800000
#define EMB_D 128
#define HID_D 256
#define OUT_D 128
#define NGRAPH 256

#define SCAN_B ((N_NODES + 256) / 256)   // 196 blocks covers N_NODES+1 slots
#define MAX_CSR (N_EDGES + 7 * N_NODES)  // padded-row capacity
#define NPANEL ((N_NODES + 63) / 64)     // 782 row-panels of 64

typedef __attribute__((ext_vector_type(8))) short short8;
typedef __attribute__((ext_vector_type(4))) float floatx4;
typedef __attribute__((ext_vector_type(4))) unsigned short ushortx4;
typedef __attribute__((ext_vector_type(8))) unsigned short ushortx8;

__device__ inline void bf16split(float x, short& hi, short& lo) {
    __hip_bfloat16 h = __float2bfloat16(x);
    float r = x - __bfloat162float(h);
    __hip_bfloat16 l = __float2bfloat16(r);
    hi = *reinterpret_cast<short*>(&h);
    lo = *reinterpret_cast<short*>(&l);
}

__device__ inline unsigned short f2b(float f) {
    __hip_bfloat16 h = __float2bfloat16(f);
    return *reinterpret_cast<unsigned short*>(&h);
}

__device__ inline float b2f(unsigned short u) {
    union { unsigned int i; float f; } c;
    c.i = ((unsigned int)u) << 16;
    return c.f;
}

// A-fragment-major index: element (row i, col c) of a K-wide plane, KB = K/32.
// Layout: [i/64][c/32][ (i&63)/16 ][ lane=((c&31)/8)*16 + (i&15) ][ c&7 ]
__device__ inline size_t fidx(int i, int c, int KB) {
    return ((size_t)(i >> 6) * KB + (c >> 5)) * 2048
         + (size_t)((((i & 63) >> 4) << 9) + ((((c & 31) >> 3) << 4) + (i & 15)) * 8 + (c & 7));
}

template<int V> struct UV2;
template<> struct UV2<4> { using T = ushortx4; };   // D=128: 8B/lane
template<> struct UV2<8> { using T = ushortx8; };   // D=256: 16B/lane

// ---------------- rank pass: 4-shard degree histogram + per-edge rank ----------------
__global__ void rank_kernel(const int* __restrict__ dst, int* __restrict__ deg4,
                            int* __restrict__ pos) {
    int e = blockIdx.x * blockDim.x + threadIdx.x;
    if (e >= N_EDGES) return;
    pos[e] = atomicAdd(&deg4[(size_t)(e & 3) * N_NODES + dst[e]], 1);
}

// ---------------- scan phase A: merge shards, block sums (PADDED), dinv, shard bases ----
__global__ void scan_a(const int* __restrict__ deg4, int* __restrict__ degt,
                       int* __restrict__ degp, int* __restrict__ sb4,
                       int* __restrict__ bsum, float* __restrict__ dinv) {
    __shared__ int red[256];
    int t = threadIdx.x;
    int i = blockIdx.x * 256 + t;
    int pad = 0;
    if (i < N_NODES) {
        int d0 = deg4[i];
        int d1 = deg4[(size_t)N_NODES + i];
        int d2 = deg4[(size_t)2 * N_NODES + i];
        int d3 = deg4[(size_t)3 * N_NODES + i];
        int tot = d0 + d1 + d2 + d3;
        degt[i] = tot;
        pad = (tot + 7) & ~7;            // row padded to multiple of 8
        degp[i] = pad;
        dinv[i] = rsqrtf((float)tot + 1.0f);
        sb4[i] = 0;
        sb4[(size_t)N_NODES + i] = d0;
        sb4[(size_t)2 * N_NODES + i] = d0 + d1;
        sb4[(size_t)3 * N_NODES + i] = d0 + d1 + d2;
    }
    red[t] = pad;
    __syncthreads();
    for (int off = 128; off > 0; off >>= 1) {
        if (t < off) red[t] += red[t + off];
        __syncthreads();
    }
    if (t == 0) bsum[blockIdx.x] = red[0];
}

// ---------------- phase B: exclusive scan of block sums + graph boundaries (1 block) ----
__global__ void scan_b(const int* __restrict__ bsum, int* __restrict__ boff,
                       const int* __restrict__ batch, int* __restrict__ bstart) {
    int t = threadIdx.x;
    // fused: graph boundary lower_bound (batch is sorted, values < NGRAPH)
    {
        int lo = 0, hi = N_NODES;
        while (lo < hi) {
            int mid = (lo + hi) >> 1;
            if (batch[mid] < t) lo = mid + 1;
            else hi = mid;
        }
        bstart[t] = lo;
        if (t == 0) bstart[NGRAPH] = N_NODES;
    }
    __shared__ int s[256];
    s[t] = (t < SCAN_B) ? bsum[t] : 0;
    __syncthreads();
    for (int off = 1; off < 256; off <<= 1) {
        int v = (t >= off) ? s[t - off] : 0;
        __syncthreads();
        s[t] += v;
        __syncthreads();
    }
    if (t < SCAN_B) boff[t] = (t == 0) ? 0 : s[t - 1];
}

// ---------------- phase C: in-block scan + offset -> row_start (padded) ----------------
__global__ void scan_c(const int* __restrict__ degp, const int* __restrict__ boff,
                       int* __restrict__ row_start) {
    __shared__ int s[256];
    int t = threadIdx.x;
    int i = blockIdx.x * 256 + t;
    int v = (i < N_NODES) ? degp[i] : 0;
    s[t] = v;
    __syncthreads();
    for (int off = 1; off < 256; off <<= 1) {
        int x = (t >= off) ? s[t - off] : 0;
        __syncthreads();
        s[t] += x;
        __syncthreads();
    }
    int excl = s[t] - v;
    int rs = boff[blockIdx.x] + excl;
    if (i <= N_NODES) row_start[i] = rs;
}

// ---------------- fill padded slots with (src=0, norm=0) sentinels ----------------
__global__ void fill_pad(const int* __restrict__ row_start, const int* __restrict__ degt,
                         int2* __restrict__ csr_sn) {
    int i = blockIdx.x * blockDim.x + threadIdx.x;
    if (i >= N_NODES) return;
    int rs = row_start[i];
    int e_true = rs + degt[i];
    int e_end = row_start[i + 1];
    for (int k = e_true; k < e_end; ++k) csr_sn[k] = make_int2(0, 0);
}

// ---------------- atomic-free CSR scatter (packed src+norm) ----------------
__global__ void scatter_kernel(const int* __restrict__ src, const int* __restrict__ dst,
                               const int* __restrict__ pos, const int* __restrict__ row_start,
                               const int* __restrict__ sb4, const float* __restrict__ dinv,
                               int2* __restrict__ csr_sn) {
    int e = blockIdx.x * blockDim.x + threadIdx.x;
    if (e >= N_EDGES) return;
    int s = src[e], d = dst[e];
    int slot = row_start[d] + sb4[(size_t)(e & 3) * N_NODES + d] + pos[e];
    csr_sn[slot] = make_int2(s, __float_as_int(dinv[s] * dinv[d]));
}

// ---------------- embedding gather -> bf16 rows ----------------
__global__ void gather_bf16(const int* __restrict__ ids, const float* __restrict__ embed,
                            unsigned short* __restrict__ X0) {
    int idx = blockIdx.x * blockDim.x + threadIdx.x;  // one float4 each
    const int V = EMB_D / 4;
    if (idx >= N_NODES * V) return;
    int row = idx / V, c = idx % V;
    float4 v = ((const float4*)embed)[(size_t)ids[row] * V + c];
    ushortx4 u;
    u[0] = f2b(v.x); u[1] = f2b(v.y); u[2] = f2b(v.z); u[3] = f2b(v.w);
    ((ushortx4*)X0)[idx] = u;
}

// ---------------- fused aggregation: one wave per node, two edges per wave ------------
// Rows padded to multiples of 8 (s=0,n=0 sentinels) -> single uniform loop.
// SPLITOUT: write result as bf16 hi/lo planes in A-FRAGMENT-MAJOR layout (GEMM A input);
// RES: residual read from the same fragment-major hi/lo planes.
template<int D, bool HASB, bool RES, bool RELU, bool SPLITOUT>
__global__ __launch_bounds__(256) void agg_node(
        const int* __restrict__ row_start, const int2* __restrict__ csr_sn,
        const float* __restrict__ dinv, const unsigned short* __restrict__ H,
        const float* __restrict__ b, float* __restrict__ OUTF,
        unsigned short* __restrict__ Phi, unsigned short* __restrict__ Plo) {
    constexpr int V2 = D / 32;
    using UV = typename UV2<V2>::T;
    int wave = threadIdx.x >> 6, lane = threadIdx.x & 63;
    int i = blockIdx.x * 4 + wave;
    if (i >= N_NODES) return;
    int h = lane >> 5, q = lane & 31;
    const int off = q * V2;
    const unsigned short* __restrict__ Hoff = H + off;
    float acc0[V2], acc1[V2];
#pragma unroll
    for (int v = 0; v < V2; ++v) { acc0[v] = 0.f; acc1[v] = 0.f; }
    int e0 = row_start[i], e1 = row_start[i + 1];
    if (e0 < e1) {
        int2 sn0 = csr_sn[e0 + h];
        int2 sn1 = csr_sn[e0 + 2 + h];
        int2 sn2 = csr_sn[e0 + 4 + h];
        int2 sn3 = csr_sn[e0 + 6 + h];
        int e = e0 + 8;
        for (;;) {
            UV u0 = *(const UV*)(Hoff + (size_t)sn0.x * D);
            UV u1 = *(const UV*)(Hoff + (size_t)sn1.x * D);
            UV u2 = *(const UV*)(Hoff + (size_t)sn2.x * D);
            UV u3 = *(const UV*)(Hoff + (size_t)sn3.x * D);
            float n0 = __int_as_float(sn0.y), n1 = __int_as_float(sn1.y);
            float n2 = __int_as_float(sn2.y), n3 = __int_as_float(sn3.y);
            bool more = (e < e1);
            int2 t0, t1, t2, t3;
            if (more) {
                t0 = csr_sn[e + h];
                t1 = csr_sn[e + 2 + h];
                t2 = csr_sn[e + 4 + h];
                t3 = csr_sn[e + 6 + h];
            }
#pragma unroll
            for (int v = 0; v < V2; ++v) acc0[v] = fmaf(b2f(u0[v]), n0, acc0[v]);
#pragma unroll
            for (int v = 0; v < V2; ++v) acc1[v] = fmaf(b2f(u1[v]), n1, acc1[v]);
#pragma unroll
            for (int v = 0; v < V2; ++v) acc0[v] = fmaf(b2f(u2[v]), n2, acc0[v]);
#pragma unroll
            for (int v = 0; v < V2; ++v) acc1[v] = fmaf(b2f(u3[v]), n3, acc1[v]);
            if (!more) break;
            sn0 = t0; sn1 = t1; sn2 = t2; sn3 = t3;
            e += 8;
        }
    }
#pragma unroll
    for (int v = 0; v < V2; ++v) {
        float s = acc0[v] + acc1[v];
        acc0[v] = s + __shfl_xor(s, 32);
    }
    if (h == 0) {
        float di = dinv[i];
        float d2 = di * di;
        UV us = *(const UV*)(Hoff + (size_t)i * D);
        size_t fi = 0;
        if (RES || SPLITOUT) fi = fidx(i, off, D / 32);
        UV rh, rl;
        if (RES) {
            rh = *(const UV*)(Phi + fi);
            rl = *(const UV*)(Plo + fi);
        }
        UV oh, ol;
#pragma unroll
        for (int v = 0; v < V2; ++v) {
            float val = acc0[v];
            val = fmaf(b2f(us[v]), d2, val);
            if (HASB) val += b[off + v];
            if (RES)  val += b2f(rh[v]) + b2f(rl[v]);
            if (RELU) val = fmaxf(val, 0.f);
            if (SPLITOUT) {
                short hh, ll;
                bf16split(val, hh, ll);
                oh[v] = (unsigned short)hh;
                ol[v] = (unsigned short)ll;
            } else {
                OUTF[(size_t)i * D + off + v] = val;
            }
        }
        if (SPLITOUT) {
            *(UV*)(Phi + fi) = oh;
            *(UV*)(Plo + fi) = ol;
        }
    }
}

// ---------------- W pre-split into B-fragment-major bf16 hi/lo (all 4 weights, 1 launch) ----
template<int K, int D>
__device__ inline void wsplit_one(int idx, const float* __restrict__ W,
                                  short* __restrict__ hi, short* __restrict__ lo) {
    int j = idx & 7;
    int l = (idx >> 3) & 63;
    int rest = idx >> 9;
    int kb = rest % (K / 32);
    int t = rest / (K / 32);
    int k = kb * 32 + (l >> 4) * 8 + j;
    int ncol = t * 16 + (l & 15);
    bf16split(W[(size_t)k * D + ncol], hi[idx], lo[idx]);
}

__global__ void wsplit_all(const float* __restrict__ W_in, const float* __restrict__ W_h1,
                           const float* __restrict__ W_h2, const float* __restrict__ W_out,
                           short* __restrict__ hi_in, short* __restrict__ lo_in,
                           short* __restrict__ hi_h1, short* __restrict__ lo_h1,
                           short* __restrict__ hi_h2, short* __restrict__ lo_h2,
                           short* __restrict__ hi_out, short* __restrict__ lo_out) {
    int idx = blockIdx.x * blockDim.x + threadIdx.x;
    constexpr int S1 = EMB_D * HID_D;          // 32768
    constexpr int S2 = S1 + HID_D * HID_D;     // 98304
    constexpr int S3 = S2 + HID_D * HID_D;     // 163840
    constexpr int S4 = S3 + HID_D * OUT_D;     // 196608
    if (idx < S1)      wsplit_one<EMB_D, HID_D>(idx,      W_in,  hi_in,  lo_in);
    else if (idx < S2) wsplit_one<HID_D, HID_D>(idx - S1, W_h1,  hi_h1,  lo_h1);
    else if (idx < S3) wsplit_one<HID_D, HID_D>(idx - S2, W_h2,  hi_h2,  lo_h2);
    else if (idx < S4) wsplit_one<HID_D, OUT_D>(idx - S3, W_out, hi_out, lo_out);
}

// ---------------- MFMA GEMM: Hout[N,D] = A[N,K] @ W[K,D] (+bias)(+relu) ----------------
// A is in fragment-major hi/lo planes -> direct coalesced global->reg fragment loads.
// NO LDS, no barriers. W is fragment-major (unchanged). 4 waves: wave w covers cols
// [w*(D/4), w*(D/4)+D/4), all 64 rows of the block's panel.
template<int K, int D, bool BIAS, bool RELU, bool OUTSPLIT>
__global__ __launch_bounds__(256) void gemm_mfma(
        const unsigned short* __restrict__ Ahi_g, const unsigned short* __restrict__ Alo_g,
        const short* __restrict__ Whi, const short* __restrict__ Wlo,
        const float* __restrict__ b, unsigned short* __restrict__ OutB,
        unsigned short* __restrict__ OutHi, unsigned short* __restrict__ OutLo, int n) {
    constexpr int NT = D / 64;
    constexpr int KB = K / 32;
    int wave = threadIdx.x >> 6, lane = threadIdx.x & 63;
    int quad = lane >> 4, lane15 = lane & 15;
    int row0 = blockIdx.x * 64;

    const unsigned short* __restrict__ Ah = Ahi_g + (size_t)(row0 >> 6) * KB * 2048 + lane * 8;
    const unsigned short* __restrict__ Al = Alo_g + (size_t)(row0 >> 6) * KB * 2048 + lane * 8;

    floatx4 acc[4][NT];
#pragma unroll
    for (int mt = 0; mt < 4; ++mt)
#pragma unroll
        for (int nt = 0; nt < NT; ++nt)
            acc[mt][nt] = (floatx4){0.f, 0.f, 0.f, 0.f};

#pragma unroll
    for (int kb = 0; kb < KB; ++kb) {
        short8 ah[4], al[4];
#pragma unroll
        for (int mt = 0; mt < 4; ++mt) {
            ah[mt] = *(const short8*)(Ah + kb * 2048 + mt * 512);
            al[mt] = *(const short8*)(Al + kb * 2048 + mt * 512);
        }
        short8 bh[NT], bl[NT];
#pragma unroll
        for (int nt = 0; nt < NT; ++nt) {
            int t = wave * NT + nt;
            size_t fb = ((size_t)(t * KB + kb) * 64 + lane) * 8;
            bh[nt] = *(const short8*)&Whi[fb];
            bl[nt] = *(const short8*)&Wlo[fb];
        }
#pragma unroll
        for (int mt = 0; mt < 4; ++mt)
#pragma unroll
            for (int nt = 0; nt < NT; ++nt) {
                acc[mt][nt] = __builtin_amdgcn_mfma_f32_16x16x32_bf16(ah[mt], bh[nt], acc[mt][nt], 0, 0, 0);
                acc[mt][nt] = __builtin_amdgcn_mfma_f32_16x16x32_bf16(ah[mt], bl[nt], acc[mt][nt], 0, 0, 0);
                acc[mt][nt] = __builtin_amdgcn_mfma_f32_16x16x32_bf16(al[mt], bh[nt], acc[mt][nt], 0, 0, 0);
            }
    }

#pragma unroll
    for (int mt = 0; mt < 4; ++mt) {
#pragma unroll
        for (int nt = 0; nt < NT; ++nt) {
            int col = wave * (NT * 16) + nt * 16 + lane15;
            float bj = BIAS ? b[col] : 0.f;
#pragma unroll
            for (int reg = 0; reg < 4; ++reg) {
                int row = row0 + mt * 16 + quad * 4 + reg;
                if (row < n) {
                    float v = acc[mt][nt][reg] + bj;
                    if (RELU) v = fmaxf(v, 0.f);
                    if (OUTSPLIT) {
                        short hh, ll;
                        bf16split(v, hh, ll);
                        size_t fo = fidx(row, col, D / 32);
                        OutHi[fo] = (unsigned short)hh;
                        OutLo[fo] = (unsigned short)ll;
                    } else {
                        OutB[(size_t)row * D + col] = f2b(v);
                    }
                }
            }
        }
    }
}

// ---------------- readout: one block per graph, atomic-free mean ----------------
__global__ void graph_mean(const int* __restrict__ bstart, const float* __restrict__ X,
                           float* __restrict__ out) {
    int g = blockIdx.x;
    int r0 = bstart[g], r1 = bstart[g + 1];
    int col = threadIdx.x & 127, rr = threadIdx.x >> 7;  // 2 rows in flight
    float acc = 0.f;
    for (int r = r0 + rr; r < r1; r += 2)
        acc += X[(size_t)r * OUT_D + col];
    __shared__ float sh[128];
    if (rr == 1) sh[col] = acc;
    __syncthreads();
    if (rr == 0) {
        float tot = acc + sh[col];
        int c = r1 - r0;
        out[(size_t)g * OUT_D + col] = tot / (float)(c > 0 ? c : 1);
    }
}

extern "C" void kernel_launch(void* const* d_in, const int* in_sizes, int n_in,
                              void* d_out, int out_size, void* d_ws, size_t ws_size,
                              hipStream_t stream) {
    const int* node_ids = (const int*)d_in[0];
    const int* edge_index = (const int*)d_in[1];
    const int* batch = (const int*)d_in[2];
    const float* embed = (const float*)d_in[3];
    const float* W_in  = (const float*)d_in[4];
    const float* b_in  = (const float*)d_in[5];
    const float* W_h1  = (const float*)d_in[6];
    const float* b_h1  = (const float*)d_in[7];
    const float* W_h2  = (const float*)d_in[8];
    const float* b_h2  = (const float*)d_in[9];
    const float* W_out = (const float*)d_in[10];
    const float* b_out = (const float*)d_in[11];
    float* out = (float*)d_out;

    const int* src = edge_index;
    const int* dst = edge_index + N_EDGES;

    char* w = (char*)d_ws;
    size_t o = 0;
    auto alloc = [&](size_t bytes) -> void* {
        void* p = w + o;
        o = (o + bytes + 255) & ~(size_t)255;
        return p;
    };
    int*   deg4     = (int*)alloc((size_t)4 * N_NODES * sizeof(int));
    int*   sb4      = (int*)alloc((size_t)4 * N_NODES * sizeof(int));
    int*   degt     = (int*)alloc((size_t)N_NODES * sizeof(int));
    int*   degp     = (int*)alloc((size_t)N_NODES * sizeof(int));
    int*   pos      = (int*)alloc((size_t)N_EDGES * sizeof(int));
    float* dinv     = (float*)alloc((size_t)N_NODES * sizeof(float));
    int*   bstart   = (int*)alloc((size_t)(NGRAPH + 1) * sizeof(int));
    int*   row_start= (int*)alloc((size_t)(N_NODES + 1) * sizeof(int));
    int*   bsum     = (int*)alloc((size_t)SCAN_B * sizeof(int));
    int*   boff     = (int*)alloc((size_t)SCAN_B * sizeof(int));
    int2*  csr_sn   = (int2*)alloc((size_t)MAX_CSR * sizeof(int2));
    // fragment-major hi/lo planes (padded to whole 64-row panels)
    unsigned short* Xhi = (unsigned short*)alloc((size_t)NPANEL * 8 * 2048 * sizeof(short));
    unsigned short* Xlo = (unsigned short*)alloc((size_t)NPANEL * 8 * 2048 * sizeof(short));
    unsigned short* H16 = (unsigned short*)alloc((size_t)N_NODES * HID_D * sizeof(short)); // row-major bf16 gather operand
    unsigned short* A1hi = (unsigned short*)alloc((size_t)NPANEL * 4 * 2048 * sizeof(short));
    unsigned short* A1lo = (unsigned short*)alloc((size_t)NPANEL * 4 * 2048 * sizeof(short));
    float* A1       = (float*)alloc((size_t)N_NODES * 128 * sizeof(float));       // final agg out (fp32)
    short* Whi_in   = (short*)alloc((size_t)EMB_D * HID_D * sizeof(short));
    short* Wlo_in   = (short*)alloc((size_t)EMB_D * HID_D * sizeof(short));
    short* Whi_h1   = (short*)alloc((size_t)HID_D * HID_D * sizeof(short));
    short* Wlo_h1   = (short*)alloc((size_t)HID_D * HID_D * sizeof(short));
    short* Whi_h2   = (short*)alloc((size_t)HID_D * HID_D * sizeof(short));
    short* Wlo_h2   = (short*)alloc((size_t)HID_D * HID_D * sizeof(short));
    short* Whi_out  = (short*)alloc((size_t)HID_D * OUT_D * sizeof(short));
    short* Wlo_out  = (short*)alloc((size_t)HID_D * OUT_D * sizeof(short));
    unsigned short* E16 = H16;               // layer-1 bf16 embeddings alias
    unsigned short* H4  = H16;               // layer-4 bf16 GEMM out [N,128] alias
    (void)ws_size;

    hipMemsetAsync(deg4, 0, (size_t)4 * N_NODES * sizeof(int), stream);

    rank_kernel<<<(N_EDGES + 255) / 256, 256, 0, stream>>>(dst, deg4, pos);
    scan_a<<<SCAN_B, 256, 0, stream>>>(deg4, degt, degp, sb4, bsum, dinv);
    scan_b<<<1, 256, 0, stream>>>(bsum, boff, batch, bstart);   // + fused graph boundaries
    scan_c<<<SCAN_B, 256, 0, stream>>>(degp, boff, row_start);
    fill_pad<<<(N_NODES + 255) / 256, 256, 0, stream>>>(row_start, degt, csr_sn);
    scatter_kernel<<<(N_EDGES + 255) / 256, 256, 0, stream>>>(src, dst, pos, row_start,
                                                              sb4, dinv, csr_sn);

    wsplit_all<<<(196608 + 255) / 256, 256, 0, stream>>>(
        W_in, W_h1, W_h2, W_out,
        Whi_in, Wlo_in, Whi_h1, Wlo_h1, Whi_h2, Wlo_h2, Whi_out, Wlo_out);

    const int gemm_grid = NPANEL;            // 64 rows per block, exact panel cover
    const int agg_grid = (N_NODES + 3) / 4;

    // ---- Layer 1: gather emb (bf16, 128), agg at 128 (frag-split out), GEMM 128->256 +b+relu ----
    gather_bf16<<<(N_NODES * (EMB_D / 4) + 255) / 256, 256, 0, stream>>>(node_ids, embed, E16);
    agg_node<128, false, false, false, true><<<agg_grid, 256, 0, stream>>>(
        row_start, csr_sn, dinv, E16, nullptr, nullptr, A1hi, A1lo);
    gemm_mfma<128, 256, true, true, true><<<gemm_grid, 256, 0, stream>>>(
        A1hi, A1lo, Whi_in, Wlo_in, b_in, nullptr, Xhi, Xlo, N_NODES);

    // ---- Layer 2: GEMM 256->256 (bf16 out), fused agg+self+bias+residual+relu (frag-split out) ----
    gemm_mfma<256, 256, false, false, false><<<gemm_grid, 256, 0, stream>>>(
        Xhi, Xlo, Whi_h1, Wlo_h1, nullptr, H16, nullptr, nullptr, N_NODES);
    agg_node<256, true, true, true, true><<<agg_grid, 256, 0, stream>>>(
        row_start, csr_sn, dinv, H16, b_h1, nullptr, Xhi, Xlo);

    // ---- Layer 3: same ----
    gemm_mfma<256, 256, false, false, false><<<gemm_grid, 256, 0, stream>>>(
        Xhi, Xlo, Whi_h2, Wlo_h2, nullptr, H16, nullptr, nullptr, N_NODES);
    agg_node<256, true, true, true, true><<<agg_grid, 256, 0, stream>>>(
        row_start, csr_sn, dinv, H16, b_h2, nullptr, Xhi, Xlo);

    // ---- Layer 4: GEMM 256->128 (bf16 out), agg at 128 +bias -> fp32 ----
    gemm_mfma<256, 128, false, false, false><<<gemm_grid, 256, 0, stream>>>(
        Xhi, Xlo, Whi_out, Wlo_out, nullptr, H4, nullptr, nullptr, N_NODES);
    agg_node<128, true, false, false, false><<<agg_grid, 256, 0, stream>>>(
        row_start, csr_sn, dinv, H4, b_out, A1, nullptr, nullptr);

    // ---- readout: atomic-free per-graph mean (batch sorted) ----
    graph_mean<<<NGRAPH, 256, 0, stream>>>(bstart, A1, out);
}

// Round 11
// 542.881 us; speedup vs baseline: 1.0942x; 1.0942x over previous
//
#include <hip/hip_runtime.h>
#include <hip/hip_bf16.h>

#define N_NODES 50000
#define N_EDGES 800000
#define EMB_D 128
#define HID_D 256
#define OUT_D 128
#define NGRAPH 256

#define SCAN_B ((N_NODES + 256) / 256)    // 196 blocks covers N_NODES+1 slots
#define MAX_CSR (N_EDGES + 15 * N_NODES)  // pad-16 row capacity

typedef __attribute__((ext_vector_type(8))) short short8;
typedef __attribute__((ext_vector_type(4))) float floatx4;
typedef __attribute__((ext_vector_type(4))) unsigned short ushortx4;
typedef __attribute__((ext_vector_type(8))) unsigned short ushortx8;

__device__ inline void bf16split(float x, short& hi, short& lo) {
    __hip_bfloat16 h = __float2bfloat16(x);
    float r = x - __bfloat162float(h);
    __hip_bfloat16 l = __float2bfloat16(r);
    hi = *reinterpret_cast<short*>(&h);
    lo = *reinterpret_cast<short*>(&l);
}

__device__ inline unsigned short f2b(float f) {
    __hip_bfloat16 h = __float2bfloat16(f);
    return *reinterpret_cast<unsigned short*>(&h);
}

__device__ inline float b2f(unsigned short u) {
    union { unsigned int i; float f; } c;
    c.i = ((unsigned int)u) << 16;
    return c.f;
}

template<int V> struct UV2;
template<> struct UV2<4> { using T = ushortx4; };   // D=128: 8B/lane
template<> struct UV2<8> { using T = ushortx8; };   // D=256: 16B/lane

// ---------------- rank pass: 4-shard degree histogram + per-edge rank ----------------
__global__ void rank_kernel(const int* __restrict__ dst, int* __restrict__ deg4,
                            int* __restrict__ pos) {
    int e = blockIdx.x * blockDim.x + threadIdx.x;
    if (e >= N_EDGES) return;
    pos[e] = atomicAdd(&deg4[(size_t)(e & 3) * N_NODES + dst[e]], 1);
}

// ---------------- scan phase A: merge shards, block sums (PAD-16), dinv, shard bases ----
__global__ void scan_a(const int* __restrict__ deg4, int* __restrict__ degt,
                       int* __restrict__ degp, int* __restrict__ sb4,
                       int* __restrict__ bsum, float* __restrict__ dinv) {
    __shared__ int red[256];
    int t = threadIdx.x;
    int i = blockIdx.x * 256 + t;
    int pad = 0;
    if (i < N_NODES) {
        int d0 = deg4[i];
        int d1 = deg4[(size_t)N_NODES + i];
        int d2 = deg4[(size_t)2 * N_NODES + i];
        int d3 = deg4[(size_t)3 * N_NODES + i];
        int tot = d0 + d1 + d2 + d3;
        degt[i] = tot;
        pad = (tot + 15) & ~15;          // row padded to multiple of 16
        degp[i] = pad;
        dinv[i] = rsqrtf((float)tot + 1.0f);
        sb4[i] = 0;
        sb4[(size_t)N_NODES + i] = d0;
        sb4[(size_t)2 * N_NODES + i] = d0 + d1;
        sb4[(size_t)3 * N_NODES + i] = d0 + d1 + d2;
    }
    red[t] = pad;
    __syncthreads();
    for (int off = 128; off > 0; off >>= 1) {
        if (t < off) red[t] += red[t + off];
        __syncthreads();
    }
    if (t == 0) bsum[blockIdx.x] = red[0];
}

// ---------------- phase B: exclusive scan of block sums + graph boundaries (1 block) ----
__global__ void scan_b(const int* __restrict__ bsum, int* __restrict__ boff,
                       const int* __restrict__ batch, int* __restrict__ bstart) {
    int t = threadIdx.x;
    {
        int lo = 0, hi = N_NODES;
        while (lo < hi) {
            int mid = (lo + hi) >> 1;
            if (batch[mid] < t) lo = mid + 1;
            else hi = mid;
        }
        bstart[t] = lo;
        if (t == 0) bstart[NGRAPH] = N_NODES;
    }
    __shared__ int s[256];
    s[t] = (t < SCAN_B) ? bsum[t] : 0;
    __syncthreads();
    for (int off = 1; off < 256; off <<= 1) {
        int v = (t >= off) ? s[t - off] : 0;
        __syncthreads();
        s[t] += v;
        __syncthreads();
    }
    if (t < SCAN_B) boff[t] = (t == 0) ? 0 : s[t - 1];
}

// ---------------- phase C: in-block scan + offset -> row_start (padded) ----------------
__global__ void scan_c(const int* __restrict__ degp, const int* __restrict__ boff,
                       int* __restrict__ row_start) {
    __shared__ int s[256];
    int t = threadIdx.x;
    int i = blockIdx.x * 256 + t;
    int v = (i < N_NODES) ? degp[i] : 0;
    s[t] = v;
    __syncthreads();
    for (int off = 1; off < 256; off <<= 1) {
        int x = (t >= off) ? s[t - off] : 0;
        __syncthreads();
        s[t] += x;
        __syncthreads();
    }
    int excl = s[t] - v;
    int rs = boff[blockIdx.x] + excl;
    if (i <= N_NODES) row_start[i] = rs;
}

// ---------------- fill padded slots with (src=0, norm=0) sentinels ----------------
__global__ void fill_pad(const int* __restrict__ row_start, const int* __restrict__ degt,
                         int2* __restrict__ csr_sn) {
    int i = blockIdx.x * blockDim.x + threadIdx.x;
    if (i >= N_NODES) return;
    int rs = row_start[i];
    int e_true = rs + degt[i];
    int e_end = row_start[i + 1];
    for (int k = e_true; k < e_end; ++k) csr_sn[k] = make_int2(0, 0);
}

// ---------------- atomic-free CSR scatter (packed src+norm) ----------------
__global__ void scatter_kernel(const int* __restrict__ src, const int* __restrict__ dst,
                               const int* __restrict__ pos, const int* __restrict__ row_start,
                               const int* __restrict__ sb4, const float* __restrict__ dinv,
                               int2* __restrict__ csr_sn) {
    int e = blockIdx.x * blockDim.x + threadIdx.x;
    if (e >= N_EDGES) return;
    int s = src[e], d = dst[e];
    int slot = row_start[d] + sb4[(size_t)(e & 3) * N_NODES + d] + pos[e];
    csr_sn[slot] = make_int2(s, __float_as_int(dinv[s] * dinv[d]));
}

// ---------------- embedding gather -> bf16 rows ----------------
__global__ void gather_bf16(const int* __restrict__ ids, const float* __restrict__ embed,
                            unsigned short* __restrict__ X0) {
    int idx = blockIdx.x * blockDim.x + threadIdx.x;  // one float4 each
    const int V = EMB_D / 4;
    if (idx >= N_NODES * V) return;
    int row = idx / V, c = idx % V;
    float4 v = ((const float4*)embed)[(size_t)ids[row] * V + c];
    ushortx4 u;
    u[0] = f2b(v.x); u[1] = f2b(v.y); u[2] = f2b(v.z); u[3] = f2b(v.w);
    ((ushortx4*)X0)[idx] = u;
}

// ---------------- fused aggregation: one wave per node, 16 edges per iteration --------
// Rows padded to multiples of 16 (s=0,n=0 sentinels) -> uniform loop, 8 gathers in
// flight per half-wave (deep MLP). SPLITOUT: bf16 hi/lo ROW-MAJOR planes (GEMM A).
template<int D, bool HASB, bool RES, bool RELU, bool SPLITOUT>
__global__ __launch_bounds__(256) void agg_node(
        const int* __restrict__ row_start, const int2* __restrict__ csr_sn,
        const float* __restrict__ dinv, const unsigned short* __restrict__ H,
        const float* __restrict__ b, float* __restrict__ OUTF,
        unsigned short* __restrict__ Phi, unsigned short* __restrict__ Plo) {
    constexpr int V2 = D / 32;
    using UV = typename UV2<V2>::T;
    int wave = threadIdx.x >> 6, lane = threadIdx.x & 63;
    int i = blockIdx.x * 4 + wave;
    if (i >= N_NODES) return;
    int h = lane >> 5, q = lane & 31;
    const int off = q * V2;
    const unsigned short* __restrict__ Hoff = H + off;
    float acc0[V2], acc1[V2];
#pragma unroll
    for (int v = 0; v < V2; ++v) { acc0[v] = 0.f; acc1[v] = 0.f; }
    int e0 = row_start[i], e1 = row_start[i + 1];
    if (e0 < e1) {
        int2 sn[8];
#pragma unroll
        for (int k = 0; k < 8; ++k) sn[k] = csr_sn[e0 + 2 * k + h];
        int e = e0 + 16;
        for (;;) {
            UV u[8];
#pragma unroll
            for (int k = 0; k < 8; ++k) u[k] = *(const UV*)(Hoff + (size_t)sn[k].x * D);
            float nn[8];
#pragma unroll
            for (int k = 0; k < 8; ++k) nn[k] = __int_as_float(sn[k].y);
            bool more = (e < e1);
            int2 t[8];
            if (more) {
#pragma unroll
                for (int k = 0; k < 8; ++k) t[k] = csr_sn[e + 2 * k + h];
            }
#pragma unroll
            for (int k = 0; k < 8; ++k) {
                if (k & 1) {
#pragma unroll
                    for (int v = 0; v < V2; ++v) acc1[v] = fmaf(b2f(u[k][v]), nn[k], acc1[v]);
                } else {
#pragma unroll
                    for (int v = 0; v < V2; ++v) acc0[v] = fmaf(b2f(u[k][v]), nn[k], acc0[v]);
                }
            }
            if (!more) break;
#pragma unroll
            for (int k = 0; k < 8; ++k) sn[k] = t[k];
            e += 16;
        }
    }
#pragma unroll
    for (int v = 0; v < V2; ++v) {
        float s = acc0[v] + acc1[v];
        acc0[v] = s + __shfl_xor(s, 32);
    }
    if (h == 0) {
        float di = dinv[i];
        float d2 = di * di;
        UV us = *(const UV*)(Hoff + (size_t)i * D);
        UV rh, rl;
        if (RES) {
            rh = *(const UV*)(Phi + (size_t)i * D + off);
            rl = *(const UV*)(Plo + (size_t)i * D + off);
        }
        UV oh, ol;
#pragma unroll
        for (int v = 0; v < V2; ++v) {
            float val = acc0[v];
            val = fmaf(b2f(us[v]), d2, val);
            if (HASB) val += b[off + v];
            if (RES)  val += b2f(rh[v]) + b2f(rl[v]);
            if (RELU) val = fmaxf(val, 0.f);
            if (SPLITOUT) {
                short hh, ll;
                bf16split(val, hh, ll);
                oh[v] = (unsigned short)hh;
                ol[v] = (unsigned short)ll;
            } else {
                OUTF[(size_t)i * D + off + v] = val;
            }
        }
        if (SPLITOUT) {
            *(UV*)(Phi + (size_t)i * D + off) = oh;
            *(UV*)(Plo + (size_t)i * D + off) = ol;
        }
    }
}

// ---------------- W pre-split into B-fragment-major bf16 hi/lo (all 4 weights, 1 launch) ----
template<int K, int D>
__device__ inline void wsplit_one(int idx, const float* __restrict__ W,
                                  short* __restrict__ hi, short* __restrict__ lo) {
    int j = idx & 7;
    int l = (idx >> 3) & 63;
    int rest = idx >> 9;
    int kb = rest % (K / 32);
    int t = rest / (K / 32);
    int k = kb * 32 + (l >> 4) * 8 + j;
    int ncol = t * 16 + (l & 15);
    bf16split(W[(size_t)k * D + ncol], hi[idx], lo[idx]);
}

__global__ void wsplit_all(const float* __restrict__ W_in, const float* __restrict__ W_h1,
                           const float* __restrict__ W_h2, const float* __restrict__ W_out,
                           short* __restrict__ hi_in, short* __restrict__ lo_in,
                           short* __restrict__ hi_h1, short* __restrict__ lo_h1,
                           short* __restrict__ hi_h2, short* __restrict__ lo_h2,
                           short* __restrict__ hi_out, short* __restrict__ lo_out) {
    int idx = blockIdx.x * blockDim.x + threadIdx.x;
    constexpr int S1 = EMB_D * HID_D;          // 32768
    constexpr int S2 = S1 + HID_D * HID_D;     // 98304
    constexpr int S3 = S2 + HID_D * HID_D;     // 163840
    constexpr int S4 = S3 + HID_D * OUT_D;     // 196608
    if (idx < S1)      wsplit_one<EMB_D, HID_D>(idx,      W_in,  hi_in,  lo_in);
    else if (idx < S2) wsplit_one<HID_D, HID_D>(idx - S1, W_h1,  hi_h1,  lo_h1);
    else if (idx < S3) wsplit_one<HID_D, HID_D>(idx - S2, W_h2,  hi_h2,  lo_h2);
    else if (idx < S4) wsplit_one<HID_D, OUT_D>(idx - S3, W_out, hi_out, lo_out);
}

// ---------------- MFMA GEMM: Hout[N,D] = A[N,K] @ W[K,D] (+bias)(+relu) ----------------
// A comes PRE-SPLIT as row-major bf16 hi/lo planes -> staging is a pure vector copy.
template<int K, int D, bool BIAS, bool RELU, bool OUTSPLIT>
__global__ __launch_bounds__(256) void gemm_mfma(
        const unsigned short* __restrict__ Ahi_g, const unsigned short* __restrict__ Alo_g,
        const short* __restrict__ Whi, const short* __restrict__ Wlo,
        const float* __restrict__ b, unsigned short* __restrict__ OutB,
        unsigned short* __restrict__ OutHi, unsigned short* __restrict__ OutLo, int n) {
    constexpr int LDK = K + 8;
    constexpr int NT = D / 64;
    constexpr int KB = K / 32;
    __shared__ __align__(16) short Ahi[64 * LDK];
    __shared__ __align__(16) short Alo[64 * LDK];

    int row0 = blockIdx.x * 64;
    constexpr int NF8 = 64 * (K / 8);
    for (int idx = threadIdx.x; idx < NF8; idx += 256) {
        int r = idx / (K / 8), c8 = idx % (K / 8);
        ushortx8 vh = {0, 0, 0, 0, 0, 0, 0, 0};
        ushortx8 vl = {0, 0, 0, 0, 0, 0, 0, 0};
        if (row0 + r < n) {
            vh = *(const ushortx8*)(Ahi_g + (size_t)(row0 + r) * K + c8 * 8);
            vl = *(const ushortx8*)(Alo_g + (size_t)(row0 + r) * K + c8 * 8);
        }
        *(ushortx8*)&Ahi[r * LDK + c8 * 8] = vh;
        *(ushortx8*)&Alo[r * LDK + c8 * 8] = vl;
    }
    __syncthreads();

    int wave = threadIdx.x >> 6, lane = threadIdx.x & 63;
    int quad = lane >> 4, lane15 = lane & 15;

    floatx4 acc[4][NT];
#pragma unroll
    for (int mt = 0; mt < 4; ++mt)
#pragma unroll
        for (int nt = 0; nt < NT; ++nt)
            acc[mt][nt] = (floatx4){0.f, 0.f, 0.f, 0.f};

#pragma unroll
    for (int kb = 0; kb < KB; ++kb) {
        short8 ah[4], al[4];
#pragma unroll
        for (int mt = 0; mt < 4; ++mt) {
            int addr = (mt * 16 + lane15) * LDK + kb * 32 + quad * 8;
            ah[mt] = *(const short8*)&Ahi[addr];
            al[mt] = *(const short8*)&Alo[addr];
        }
        short8 bh[NT], bl[NT];
#pragma unroll
        for (int nt = 0; nt < NT; ++nt) {
            int t = wave * NT + nt;
            size_t fb = ((size_t)(t * KB + kb) * 64 + lane) * 8;
            bh[nt] = *(const short8*)&Whi[fb];
            bl[nt] = *(const short8*)&Wlo[fb];
        }
#pragma unroll
        for (int mt = 0; mt < 4; ++mt)
#pragma unroll
            for (int nt = 0; nt < NT; ++nt) {
                acc[mt][nt] = __builtin_amdgcn_mfma_f32_16x16x32_bf16(ah[mt], bh[nt], acc[mt][nt], 0, 0, 0);
                acc[mt][nt] = __builtin_amdgcn_mfma_f32_16x16x32_bf16(ah[mt], bl[nt], acc[mt][nt], 0, 0, 0);
                acc[mt][nt] = __builtin_amdgcn_mfma_f32_16x16x32_bf16(al[mt], bh[nt], acc[mt][nt], 0, 0, 0);
            }
    }

#pragma unroll
    for (int mt = 0; mt < 4; ++mt) {
#pragma unroll
        for (int nt = 0; nt < NT; ++nt) {
            int col = wave * (NT * 16) + nt * 16 + lane15;
            float bj = BIAS ? b[col] : 0.f;
#pragma unroll
            for (int reg = 0; reg < 4; ++reg) {
                int row = row0 + mt * 16 + quad * 4 + reg;
                if (row < n) {
                    float v = acc[mt][nt][reg] + bj;
                    if (RELU) v = fmaxf(v, 0.f);
                    if (OUTSPLIT) {
                        short hh, ll;
                        bf16split(v, hh, ll);
                        OutHi[(size_t)row * D + col] = (unsigned short)hh;
                        OutLo[(size_t)row * D + col] = (unsigned short)ll;
                    } else {
                        OutB[(size_t)row * D + col] = f2b(v);
                    }
                }
            }
        }
    }
}

// ---------------- readout: one block per graph, atomic-free mean ----------------
__global__ void graph_mean(const int* __restrict__ bstart, const float* __restrict__ X,
                           float* __restrict__ out) {
    int g = blockIdx.x;
    int r0 = bstart[g], r1 = bstart[g + 1];
    int col = threadIdx.x & 127, rr = threadIdx.x >> 7;  // 2 rows in flight
    float acc = 0.f;
    for (int r = r0 + rr; r < r1; r += 2)
        acc += X[(size_t)r * OUT_D + col];
    __shared__ float sh[128];
    if (rr == 1) sh[col] = acc;
    __syncthreads();
    if (rr == 0) {
        float tot = acc + sh[col];
        int c = r1 - r0;
        out[(size_t)g * OUT_D + col] = tot / (float)(c > 0 ? c : 1);
    }
}

extern "C" void kernel_launch(void* const* d_in, const int* in_sizes, int n_in,
                              void* d_out, int out_size, void* d_ws, size_t ws_size,
                              hipStream_t stream) {
    const int* node_ids = (const int*)d_in[0];
    const int* edge_index = (const int*)d_in[1];
    const int* batch = (const int*)d_in[2];
    const float* embed = (const float*)d_in[3];
    const float* W_in  = (const float*)d_in[4];
    const float* b_in  = (const float*)d_in[5];
    const float* W_h1  = (const float*)d_in[6];
    const float* b_h1  = (const float*)d_in[7];
    const float* W_h2  = (const float*)d_in[8];
    const float* b_h2  = (const float*)d_in[9];
    const float* W_out = (const float*)d_in[10];
    const float* b_out = (const float*)d_in[11];
    float* out = (float*)d_out;

    const int* src = edge_index;
    const int* dst = edge_index + N_EDGES;

    char* w = (char*)d_ws;
    size_t o = 0;
    auto alloc = [&](size_t bytes) -> void* {
        void* p = w + o;
        o = (o + bytes + 255) & ~(size_t)255;
        return p;
    };
    int*   deg4     = (int*)alloc((size_t)4 * N_NODES * sizeof(int));
    int*   sb4      = (int*)alloc((size_t)4 * N_NODES * sizeof(int));
    int*   degt     = (int*)alloc((size_t)N_NODES * sizeof(int));
    int*   degp     = (int*)alloc((size_t)N_NODES * sizeof(int));
    int*   pos      = (int*)alloc((size_t)N_EDGES * sizeof(int));
    float* dinv     = (float*)alloc((size_t)N_NODES * sizeof(float));
    int*   bstart   = (int*)alloc((size_t)(NGRAPH + 1) * sizeof(int));
    int*   row_start= (int*)alloc((size_t)(N_NODES + 1) * sizeof(int));
    int*   bsum     = (int*)alloc((size_t)SCAN_B * sizeof(int));
    int*   boff     = (int*)alloc((size_t)SCAN_B * sizeof(int));
    int2*  csr_sn   = (int2*)alloc((size_t)MAX_CSR * sizeof(int2));
    unsigned short* Xhi = (unsigned short*)alloc((size_t)N_NODES * HID_D * sizeof(short));
    unsigned short* Xlo = (unsigned short*)alloc((size_t)N_NODES * HID_D * sizeof(short));
    unsigned short* H16 = (unsigned short*)alloc((size_t)N_NODES * HID_D * sizeof(short)); // bf16 gather operand
    unsigned short* A1hi = (unsigned short*)alloc((size_t)N_NODES * 128 * sizeof(short));
    unsigned short* A1lo = (unsigned short*)alloc((size_t)N_NODES * 128 * sizeof(short));
    float* A1       = (float*)alloc((size_t)N_NODES * 128 * sizeof(float));       // final agg out (fp32)
    short* Whi_in   = (short*)alloc((size_t)EMB_D * HID_D * sizeof(short));
    short* Wlo_in   = (short*)alloc((size_t)EMB_D * HID_D * sizeof(short));
    short* Whi_h1   = (short*)alloc((size_t)HID_D * HID_D * sizeof(short));
    short* Wlo_h1   = (short*)alloc((size_t)HID_D * HID_D * sizeof(short));
    short* Whi_h2   = (short*)alloc((size_t)HID_D * HID_D * sizeof(short));
    short* Wlo_h2   = (short*)alloc((size_t)HID_D * HID_D * sizeof(short));
    short* Whi_out  = (short*)alloc((size_t)HID_D * OUT_D * sizeof(short));
    short* Wlo_out  = (short*)alloc((size_t)HID_D * OUT_D * sizeof(short));
    unsigned short* E16 = H16;               // layer-1 bf16 embeddings alias
    unsigned short* H4  = H16;               // layer-4 bf16 GEMM out [N,128] alias
    (void)ws_size;

    hipMemsetAsync(deg4, 0, (size_t)4 * N_NODES * sizeof(int), stream);

    rank_kernel<<<(N_EDGES + 255) / 256, 256, 0, stream>>>(dst, deg4, pos);
    scan_a<<<SCAN_B, 256, 0, stream>>>(deg4, degt, degp, sb4, bsum, dinv);
    scan_b<<<1, 256, 0, stream>>>(bsum, boff, batch, bstart);   // + fused graph boundaries
    scan_c<<<SCAN_B, 256, 0, stream>>>(degp, boff, row_start);
    fill_pad<<<(N_NODES + 255) / 256, 256, 0, stream>>>(row_start, degt, csr_sn);
    scatter_kernel<<<(N_EDGES + 255) / 256, 256, 0, stream>>>(src, dst, pos, row_start,
                                                              sb4, dinv, csr_sn);

    wsplit_all<<<(196608 + 255) / 256, 256, 0, stream>>>(
        W_in, W_h1, W_h2, W_out,
        Whi_in, Wlo_in, Whi_h1, Wlo_h1, Whi_h2, Wlo_h2, Whi_out, Wlo_out);

    const int gemm_grid = (N_NODES + 63) / 64;
    const int agg_grid = (N_NODES + 3) / 4;

    // ---- Layer 1: gather emb (bf16, 128), agg at 128 (split out), GEMM 128->256 +b+relu (split out) ----
    gather_bf16<<<(N_NODES * (EMB_D / 4) + 255) / 256, 256, 0, stream>>>(node_ids, embed, E16);
    agg_node<128, false, false, false, true><<<agg_grid, 256, 0, stream>>>(
        row_start, csr_sn, dinv, E16, nullptr, nullptr, A1hi, A1lo);
    gemm_mfma<128, 256, true, true, true><<<gemm_grid, 256, 0, stream>>>(
        A1hi, A1lo, Whi_in, Wlo_in, b_in, nullptr, Xhi, Xlo, N_NODES);

    // ---- Layer 2: GEMM 256->256 (bf16 out), fused agg+self+bias+residual+relu (split out) ----
    gemm_mfma<256, 256, false, false, false><<<gemm_grid, 256, 0, stream>>>(
        Xhi, Xlo, Whi_h1, Wlo_h1, nullptr, H16, nullptr, nullptr, N_NODES);
    agg_node<256, true, true, true, true><<<agg_grid, 256, 0, stream>>>(
        row_start, csr_sn, dinv, H16, b_h1, nullptr, Xhi, Xlo);

    // ---- Layer 3: same ----
    gemm_mfma<256, 256, false, false, false><<<gemm_grid, 256, 0, stream>>>(
        Xhi, Xlo, Whi_h2, Wlo_h2, nullptr, H16, nullptr, nullptr, N_NODES);
    agg_node<256, true, true, true, true><<<agg_grid, 256, 0, stream>>>(
        row_start, csr_sn, dinv, H16, b_h2, nullptr, Xhi, Xlo);

    // ---- Layer 4: GEMM 256->128 (bf16 out), agg at 128 +bias -> fp32 ----
    gemm_mfma<256, 128, false, false, false><<<gemm_grid, 256, 0, stream>>>(
        Xhi, Xlo, Whi_out, Wlo_out, nullptr, H4, nullptr, nullptr, N_NODES);
    agg_node<128, true, false, false, false><<<agg_grid, 256, 0, stream>>>(
        row_start, csr_sn, dinv, H4, b_out, A1, nullptr, nullptr);

    // ---- readout: atomic-free per-graph mean (batch sorted) ----
    graph_mean<<<NGRAPH, 256, 0, stream>>>(bstart, A1, out);
}

// Round 14
// 475.164 us; speedup vs baseline: 1.2502x; 1.1425x over previous
//
#include <hip/hip_runtime.h>
#include <hip/hip_bf16.h>
#include <hip/hip_fp8.h>

#define N_NODES 50000
#define N_EDGES 800000
#define EMB_D 128
#define HID_D 256
#define OUT_D 128
#define NGRAPH 256

#define SCAN_B ((N_NODES + 256) / 256)   // 196 blocks covers N_NODES+1 slots
#define MAX_CSR (N_EDGES + 7 * N_NODES)  // pad-8 row capacity

typedef __attribute__((ext_vector_type(8))) short short8;
typedef __attribute__((ext_vector_type(4))) float floatx4;
typedef __attribute__((ext_vector_type(4))) unsigned short ushortx4;
typedef __attribute__((ext_vector_type(8))) unsigned short ushortx8;
typedef __attribute__((ext_vector_type(4))) unsigned char ucharx4;
typedef __attribute__((ext_vector_type(8))) unsigned char ucharx8;

__device__ inline void bf16split(float x, short& hi, short& lo) {
    __hip_bfloat16 h = __float2bfloat16(x);
    float r = x - __bfloat162float(h);
    __hip_bfloat16 l = __float2bfloat16(r);
    hi = *reinterpret_cast<short*>(&h);
    lo = *reinterpret_cast<short*>(&l);
}

__device__ inline unsigned short f2b(float f) {
    __hip_bfloat16 h = __float2bfloat16(f);
    return *reinterpret_cast<unsigned short*>(&h);
}

__device__ inline float b2f(unsigned short u) {
    union { unsigned int i; float f; } c;
    c.i = ((unsigned int)u) << 16;
    return c.f;
}

__device__ inline unsigned char f2f8(float f) {
    __hip_fp8_e4m3 v(f);                      // OCP e4m3 (gfx950 HW cvt)
    return (unsigned char)v.__x;
}

// message-operand element -> float (overloaded on storage type)
__device__ inline float h2f(unsigned short u) { return b2f(u); }
__device__ inline float h2f(unsigned char u) {
    __hip_fp8_e4m3 v; v.__x = (__hip_fp8_storage_t)u;
    return (float)v;
}

template<int D, typename HT> struct HVec;
template<> struct HVec<128, unsigned short> { using T = ushortx4; };  // 8B/lane
template<> struct HVec<256, unsigned short> { using T = ushortx8; };  // 16B/lane
template<> struct HVec<128, unsigned char>  { using T = ucharx4;  };  // 4B/lane
template<> struct HVec<256, unsigned char>  { using T = ucharx8;  };  // 8B/lane

// ---------------- rank pass: 4-shard degree histogram + per-edge rank ----------------
__global__ void rank_kernel(const int* __restrict__ dst, int* __restrict__ deg4,
                            int* __restrict__ pos) {
    int e = blockIdx.x * blockDim.x + threadIdx.x;
    if (e >= N_EDGES) return;
    pos[e] = atomicAdd(&deg4[(size_t)(e & 3) * N_NODES + dst[e]], 1);
}

// ---------------- scan phase A: merge shards, block sums (PAD-8), dinv, shard bases ----
__global__ void scan_a(const int* __restrict__ deg4, int* __restrict__ degt,
                       int* __restrict__ degp, int* __restrict__ sb4,
                       int* __restrict__ bsum, float* __restrict__ dinv) {
    __shared__ int red[256];
    int t = threadIdx.x;
    int i = blockIdx.x * 256 + t;
    int pad = 0;
    if (i < N_NODES) {
        int d0 = deg4[i];
        int d1 = deg4[(size_t)N_NODES + i];
        int d2 = deg4[(size_t)2 * N_NODES + i];
        int d3 = deg4[(size_t)3 * N_NODES + i];
        int tot = d0 + d1 + d2 + d3;
        degt[i] = tot;
        pad = (tot + 7) & ~7;            // row padded to multiple of 8
        degp[i] = pad;
        dinv[i] = rsqrtf((float)tot + 1.0f);
        sb4[i] = 0;
        sb4[(size_t)N_NODES + i] = d0;
        sb4[(size_t)2 * N_NODES + i] = d0 + d1;
        sb4[(size_t)3 * N_NODES + i] = d0 + d1 + d2;
    }
    red[t] = pad;
    __syncthreads();
    for (int off = 128; off > 0; off >>= 1) {
        if (t < off) red[t] += red[t + off];
        __syncthreads();
    }
    if (t == 0) bsum[blockIdx.x] = red[0];
}

// ---------------- phase B: exclusive scan of block sums + graph boundaries (1 block) ----
__global__ void scan_b(const int* __restrict__ bsum, int* __restrict__ boff,
                       const int* __restrict__ batch, int* __restrict__ bstart) {
    int t = threadIdx.x;
    {
        int lo = 0, hi = N_NODES;
        while (lo < hi) {
            int mid = (lo + hi) >> 1;
            if (batch[mid] < t) lo = mid + 1;
            else hi = mid;
        }
        bstart[t] = lo;
        if (t == 0) bstart[NGRAPH] = N_NODES;
    }
    __shared__ int s[256];
    s[t] = (t < SCAN_B) ? bsum[t] : 0;
    __syncthreads();
    for (int off = 1; off < 256; off <<= 1) {
        int v = (t >= off) ? s[t - off] : 0;
        __syncthreads();
        s[t] += v;
        __syncthreads();
    }
    if (t < SCAN_B) boff[t] = (t == 0) ? 0 : s[t - 1];
}

// ---------------- phase C: in-block scan -> row_start (padded) + fused sentinel fill ----
__global__ void scan_c(const int* __restrict__ degp, const int* __restrict__ degt,
                       const int* __restrict__ boff, int* __restrict__ row_start,
                       int2* __restrict__ csr_sn) {
    __shared__ int s[256];
    int t = threadIdx.x;
    int i = blockIdx.x * 256 + t;
    int v = (i < N_NODES) ? degp[i] : 0;
    s[t] = v;
    __syncthreads();
    for (int off = 1; off < 256; off <<= 1) {
        int x = (t >= off) ? s[t - off] : 0;
        __syncthreads();
        s[t] += x;
        __syncthreads();
    }
    int excl = s[t] - v;
    int rs = boff[blockIdx.x] + excl;
    if (i <= N_NODES) row_start[i] = rs;
    if (i < N_NODES) {
        int e_true = rs + degt[i];
        int e_end  = rs + degp[i];
        for (int k = e_true; k < e_end; ++k) csr_sn[k] = make_int2(0, 0);
    }
}

// ---------------- atomic-free CSR scatter (packed src+norm) ----------------
__global__ void scatter_kernel(const int* __restrict__ src, const int* __restrict__ dst,
                               const int* __restrict__ pos, const int* __restrict__ row_start,
                               const int* __restrict__ sb4, const float* __restrict__ dinv,
                               int2* __restrict__ csr_sn) {
    int e = blockIdx.x * blockDim.x + threadIdx.x;
    if (e >= N_EDGES) return;
    int s = src[e], d = dst[e];
    int slot = row_start[d] + sb4[(size_t)(e & 3) * N_NODES + d] + pos[e];
    csr_sn[slot] = make_int2(s, __float_as_int(dinv[s] * dinv[d]));
}

// ---------------- embedding gather -> bf16 rows ----------------
__global__ void gather_bf16(const int* __restrict__ ids, const float* __restrict__ embed,
                            unsigned short* __restrict__ X0) {
    int idx = blockIdx.x * blockDim.x + threadIdx.x;  // one float4 each
    const int V = EMB_D / 4;
    if (idx >= N_NODES * V) return;
    int row = idx / V, c = idx % V;
    float4 v = ((const float4*)embed)[(size_t)ids[row] * V + c];
    ushortx4 u;
    u[0] = f2b(v.x); u[1] = f2b(v.y); u[2] = f2b(v.z); u[3] = f2b(v.w);
    ((ushortx4*)X0)[idx] = u;
}

// ---------------- fused aggregation: one wave per node, two edges per wave ------------
// Rows padded to multiples of 8 (s=0,n=0 sentinels) -> single uniform loop.
// HT = unsigned short (bf16) or unsigned char (OCP fp8 e4m3) message operand.
// SPLITOUT: write result as bf16 hi/lo ROW-MAJOR planes (GEMM A input);
// RES: residual read from the same hi/lo planes.
template<int D, typename HT, bool HASB, bool RES, bool RELU, bool SPLITOUT>
__global__ __launch_bounds__(256) void agg_node(
        const int* __restrict__ row_start, const int2* __restrict__ csr_sn,
        const float* __restrict__ dinv, const HT* __restrict__ H,
        const float* __restrict__ b, float* __restrict__ OUTF,
        unsigned short* __restrict__ Phi, unsigned short* __restrict__ Plo) {
    constexpr int V2 = D / 32;
    using UV = typename HVec<D, HT>::T;
    using RV = typename HVec<D, unsigned short>::T;
    int wave = threadIdx.x >> 6, lane = threadIdx.x & 63;
    int i = blockIdx.x * 4 + wave;
    if (i >= N_NODES) return;
    int h = lane >> 5, q = lane & 31;
    const int off = q * V2;
    const HT* __restrict__ Hoff = H + off;
    float acc0[V2], acc1[V2];
#pragma unroll
    for (int v = 0; v < V2; ++v) { acc0[v] = 0.f; acc1[v] = 0.f; }
    int e0 = row_start[i], e1 = row_start[i + 1];
    if (e0 < e1) {
        int2 sn0 = csr_sn[e0 + h];
        int2 sn1 = csr_sn[e0 + 2 + h];
        int2 sn2 = csr_sn[e0 + 4 + h];
        int2 sn3 = csr_sn[e0 + 6 + h];
        int e = e0 + 8;
        for (;;) {
            UV u0 = *(const UV*)(Hoff + (size_t)sn0.x * D);
            UV u1 = *(const UV*)(Hoff + (size_t)sn1.x * D);
            UV u2 = *(const UV*)(Hoff + (size_t)sn2.x * D);
            UV u3 = *(const UV*)(Hoff + (size_t)sn3.x * D);
            float n0 = __int_as_float(sn0.y), n1 = __int_as_float(sn1.y);
            float n2 = __int_as_float(sn2.y), n3 = __int_as_float(sn3.y);
            bool more = (e < e1);
            int2 t0, t1, t2, t3;
            if (more) {
                t0 = csr_sn[e + h];
                t1 = csr_sn[e + 2 + h];
                t2 = csr_sn[e + 4 + h];
                t3 = csr_sn[e + 6 + h];
            }
#pragma unroll
            for (int v = 0; v < V2; ++v) acc0[v] = fmaf(h2f(u0[v]), n0, acc0[v]);
#pragma unroll
            for (int v = 0; v < V2; ++v) acc1[v] = fmaf(h2f(u1[v]), n1, acc1[v]);
#pragma unroll
            for (int v = 0; v < V2; ++v) acc0[v] = fmaf(h2f(u2[v]), n2, acc0[v]);
#pragma unroll
            for (int v = 0; v < V2; ++v) acc1[v] = fmaf(h2f(u3[v]), n3, acc1[v]);
            if (!more) break;
            sn0 = t0; sn1 = t1; sn2 = t2; sn3 = t3;
            e += 8;
        }
    }
#pragma unroll
    for (int v = 0; v < V2; ++v) {
        float s = acc0[v] + acc1[v];
        acc0[v] = s + __shfl_xor(s, 32);
    }
    if (h == 0) {
        float di = dinv[i];
        float d2 = di * di;
        UV us = *(const UV*)(Hoff + (size_t)i * D);
        RV rh, rl;
        if (RES) {
            rh = *(const RV*)(Phi + (size_t)i * D + off);
            rl = *(const RV*)(Plo + (size_t)i * D + off);
        }
        RV oh, ol;
#pragma unroll
        for (int v = 0; v < V2; ++v) {
            float val = acc0[v];
            val = fmaf(h2f(us[v]), d2, val);
            if (HASB) val += b[off + v];
            if (RES)  val += b2f(rh[v]) + b2f(rl[v]);
            if (RELU) val = fmaxf(val, 0.f);
            if (SPLITOUT) {
                short hh, ll;
                bf16split(val, hh, ll);
                oh[v] = (unsigned short)hh;
                ol[v] = (unsigned short)ll;
            } else {
                OUTF[(size_t)i * D + off + v] = val;
            }
        }
        if (SPLITOUT) {
            *(RV*)(Phi + (size_t)i * D + off) = oh;
            *(RV*)(Plo + (size_t)i * D + off) = ol;
        }
    }
}

// ---------------- W pre-split into B-fragment-major bf16 hi/lo (all 4 weights, 1 launch) ----
template<int K, int D>
__device__ inline void wsplit_one(int idx, const float* __restrict__ W,
                                  short* __restrict__ hi, short* __restrict__ lo) {
    int j = idx & 7;
    int l = (idx >> 3) & 63;
    int rest = idx >> 9;
    int kb = rest % (K / 32);
    int t = rest / (K / 32);
    int k = kb * 32 + (l >> 4) * 8 + j;
    int ncol = t * 16 + (l & 15);
    bf16split(W[(size_t)k * D + ncol], hi[idx], lo[idx]);
}

__global__ void wsplit_all(const float* __restrict__ W_in, const float* __restrict__ W_h1,
                           const float* __restrict__ W_h2, const float* __restrict__ W_out,
                           short* __restrict__ hi_in, short* __restrict__ lo_in,
                           short* __restrict__ hi_h1, short* __restrict__ lo_h1,
                           short* __restrict__ hi_h2, short* __restrict__ lo_h2,
                           short* __restrict__ hi_out, short* __restrict__ lo_out) {
    int idx = blockIdx.x * blockDim.x + threadIdx.x;
    constexpr int S1 = EMB_D * HID_D;          // 32768
    constexpr int S2 = S1 + HID_D * HID_D;     // 98304
    constexpr int S3 = S2 + HID_D * HID_D;     // 163840
    constexpr int S4 = S3 + HID_D * OUT_D;     // 196608
    if (idx < S1)      wsplit_one<EMB_D, HID_D>(idx,      W_in,  hi_in,  lo_in);
    else if (idx < S2) wsplit_one<HID_D, HID_D>(idx - S1, W_h1,  hi_h1,  lo_h1);
    else if (idx < S3) wsplit_one<HID_D, HID_D>(idx - S2, W_h2,  hi_h2,  lo_h2);
    else if (idx < S4) wsplit_one<HID_D, OUT_D>(idx - S3, W_out, hi_out, lo_out);
}

// ---------------- MFMA GEMM: Hout[N,D] = A[N,K] @ W[K,D] (+bias)(+relu) ----------------
// A comes PRE-SPLIT as row-major bf16 hi/lo planes -> staging is a pure vector copy.
// OMODE: 0 = bf16 out, 1 = bf16 hi/lo split planes, 2 = fp8 e4m3 out (message operand).
template<int K, int D, bool BIAS, bool RELU, int OMODE>
__global__ __launch_bounds__(256) void gemm_mfma(
        const unsigned short* __restrict__ Ahi_g, const unsigned short* __restrict__ Alo_g,
        const short* __restrict__ Whi, const short* __restrict__ Wlo,
        const float* __restrict__ b, void* __restrict__ OutB,
        unsigned short* __restrict__ OutHi, unsigned short* __restrict__ OutLo, int n) {
    constexpr int LDK = K + 8;
    constexpr int NT = D / 64;
    constexpr int KB = K / 32;
    __shared__ __align__(16) short Ahi[64 * LDK];
    __shared__ __align__(16) short Alo[64 * LDK];

    int row0 = blockIdx.x * 64;
    constexpr int NF8 = 64 * (K / 8);
    for (int idx = threadIdx.x; idx < NF8; idx += 256) {
        int r = idx / (K / 8), c8 = idx % (K / 8);
        ushortx8 vh = {0, 0, 0, 0, 0, 0, 0, 0};
        ushortx8 vl = {0, 0, 0, 0, 0, 0, 0, 0};
        if (row0 + r < n) {
            vh = *(const ushortx8*)(Ahi_g + (size_t)(row0 + r) * K + c8 * 8);
            vl = *(const ushortx8*)(Alo_g + (size_t)(row0 + r) * K + c8 * 8);
        }
        *(ushortx8*)&Ahi[r * LDK + c8 * 8] = vh;
        *(ushortx8*)&Alo[r * LDK + c8 * 8] = vl;
    }
    __syncthreads();

    int wave = threadIdx.x >> 6, lane = threadIdx.x & 63;
    int quad = lane >> 4, lane15 = lane & 15;

    floatx4 acc[4][NT];
#pragma unroll
    for (int mt = 0; mt < 4; ++mt)
#pragma unroll
        for (int nt = 0; nt < NT; ++nt)
            acc[mt][nt] = (floatx4){0.f, 0.f, 0.f, 0.f};

#pragma unroll
    for (int kb = 0; kb < KB; ++kb) {
        short8 ah[4], al[4];
#pragma unroll
        for (int mt = 0; mt < 4; ++mt) {
            int addr = (mt * 16 + lane15) * LDK + kb * 32 + quad * 8;
            ah[mt] = *(const short8*)&Ahi[addr];
            al[mt] = *(const short8*)&Alo[addr];
        }
        short8 bh[NT], bl[NT];
#pragma unroll
        for (int nt = 0; nt < NT; ++nt) {
            int t = wave * NT + nt;
            size_t fb = ((size_t)(t * KB + kb) * 64 + lane) * 8;
            bh[nt] = *(const short8*)&Whi[fb];
            bl[nt] = *(const short8*)&Wlo[fb];
        }
#pragma unroll
        for (int mt = 0; mt < 4; ++mt)
#pragma unroll
            for (int nt = 0; nt < NT; ++nt) {
                acc[mt][nt] = __builtin_amdgcn_mfma_f32_16x16x32_bf16(ah[mt], bh[nt], acc[mt][nt], 0, 0, 0);
                acc[mt][nt] = __builtin_amdgcn_mfma_f32_16x16x32_bf16(ah[mt], bl[nt], acc[mt][nt], 0, 0, 0);
                acc[mt][nt] = __builtin_amdgcn_mfma_f32_16x16x32_bf16(al[mt], bh[nt], acc[mt][nt], 0, 0, 0);
            }
    }

#pragma unroll
    for (int mt = 0; mt < 4; ++mt) {
#pragma unroll
        for (int nt = 0; nt < NT; ++nt) {
            int col = wave * (NT * 16) + nt * 16 + lane15;
            float bj = BIAS ? b[col] : 0.f;
#pragma unroll
            for (int reg = 0; reg < 4; ++reg) {
                int row = row0 + mt * 16 + quad * 4 + reg;
                if (row < n) {
                    float v = acc[mt][nt][reg] + bj;
                    if (RELU) v = fmaxf(v, 0.f);
                    if (OMODE == 1) {
                        short hh, ll;
                        bf16split(v, hh, ll);
                        OutHi[(size_t)row * D + col] = (unsigned short)hh;
                        OutLo[(size_t)row * D + col] = (unsigned short)ll;
                    } else if (OMODE == 2) {
                        ((unsigned char*)OutB)[(size_t)row * D + col] = f2f8(v);
                    } else {
                        ((unsigned short*)OutB)[(size_t)row * D + col] = f2b(v);
                    }
                }
            }
        }
    }
}

// ---------------- readout: one block per graph, atomic-free mean ----------------
__global__ void graph_mean(const int* __restrict__ bstart, const float* __restrict__ X,
                           float* __restrict__ out) {
    int g = blockIdx.x;
    int r0 = bstart[g], r1 = bstart[g + 1];
    int col = threadIdx.x & 127, rr = threadIdx.x >> 7;  // 2 rows in flight
    float acc = 0.f;
    for (int r = r0 + rr; r < r1; r += 2)
        acc += X[(size_t)r * OUT_D + col];
    __shared__ float sh[128];
    if (rr == 1) sh[col] = acc;
    __syncthreads();
    if (rr == 0) {
        float tot = acc + sh[col];
        int c = r1 - r0;
        out[(size_t)g * OUT_D + col] = tot / (float)(c > 0 ? c : 1);
    }
}

extern "C" void kernel_launch(void* const* d_in, const int* in_sizes, int n_in,
                              void* d_out, int out_size, void* d_ws, size_t ws_size,
                              hipStream_t stream) {
    const int* node_ids = (const int*)d_in[0];
    const int* edge_index = (const int*)d_in[1];
    const int* batch = (const int*)d_in[2];
    const float* embed = (const float*)d_in[3];
    const float* W_in  = (const float*)d_in[4];
    const float* b_in  = (const float*)d_in[5];
    const float* W_h1  = (const float*)d_in[6];
    const float* b_h1  = (const float*)d_in[7];
    const float* W_h2  = (const float*)d_in[8];
    const float* b_h2  = (const float*)d_in[9];
    const float* W_out = (const float*)d_in[10];
    const float* b_out = (const float*)d_in[11];
    float* out = (float*)d_out;

    const int* src = edge_index;
    const int* dst = edge_index + N_EDGES;

    char* w = (char*)d_ws;
    size_t o = 0;
    auto alloc = [&](size_t bytes) -> void* {
        void* p = w + o;
        o = (o + bytes + 255) & ~(size_t)255;
        return p;
    };
    int*   deg4     = (int*)alloc((size_t)4 * N_NODES * sizeof(int));
    int*   sb4      = (int*)alloc((size_t)4 * N_NODES * sizeof(int));
    int*   degt     = (int*)alloc((size_t)N_NODES * sizeof(int));
    int*   degp     = (int*)alloc((size_t)N_NODES * sizeof(int));
    int*   pos      = (int*)alloc((size_t)N_EDGES * sizeof(int));
    float* dinv     = (float*)alloc((size_t)N_NODES * sizeof(float));
    int*   bstart   = (int*)alloc((size_t)(NGRAPH + 1) * sizeof(int));
    int*   row_start= (int*)alloc((size_t)(N_NODES + 1) * sizeof(int));
    int*   bsum     = (int*)alloc((size_t)SCAN_B * sizeof(int));
    int*   boff    = (int*)alloc((size_t)SCAN_B * sizeof(int));
    int2*  csr_sn   = (int2*)alloc((size_t)MAX_CSR * sizeof(int2));
    unsigned short* Xhi = (unsigned short*)alloc((size_t)N_NODES * HID_D * sizeof(short));
    unsigned short* Xlo = (unsigned short*)alloc((size_t)N_NODES * HID_D * sizeof(short));
    unsigned short* E16 = (unsigned short*)alloc((size_t)N_NODES * EMB_D * sizeof(short));   // bf16 layer-1 operand
    unsigned char*  H8  = (unsigned char*)alloc((size_t)N_NODES * HID_D);                    // fp8 message operand (layers 2-4)
    unsigned short* A1hi = (unsigned short*)alloc((size_t)N_NODES * 128 * sizeof(short));
    unsigned short* A1lo = (unsigned short*)alloc((size_t)N_NODES * 128 * sizeof(short));
    float* A1       = (float*)alloc((size_t)N_NODES * 128 * sizeof(float));       // final agg out (fp32)
    short* Whi_in   = (short*)alloc((size_t)EMB_D * HID_D * sizeof(short));
    short* Wlo_in   = (short*)alloc((size_t)EMB_D * HID_D * sizeof(short));
    short* Whi_h1   = (short*)alloc((size_t)HID_D * HID_D * sizeof(short));
    short* Wlo_h1   = (short*)alloc((size_t)HID_D * HID_D * sizeof(short));
    short* Whi_h2   = (short*)alloc((size_t)HID_D * HID_D * sizeof(short));
    short* Wlo_h2   = (short*)alloc((size_t)HID_D * HID_D * sizeof(short));
    short* Whi_out  = (short*)alloc((size_t)HID_D * OUT_D * sizeof(short));
    short* Wlo_out  = (short*)alloc((size_t)HID_D * OUT_D * sizeof(short));
    unsigned char* H8_4 = H8;                // layer-4 fp8 GEMM out [N,128] alias
    (void)ws_size;

    hipMemsetAsync(deg4, 0, (size_t)4 * N_NODES * sizeof(int), stream);

    rank_kernel<<<(N_EDGES + 255) / 256, 256, 0, stream>>>(dst, deg4, pos);
    scan_a<<<SCAN_B, 256, 0, stream>>>(deg4, degt, degp, sb4, bsum, dinv);
    scan_b<<<1, 256, 0, stream>>>(bsum, boff, batch, bstart);   // + fused graph boundaries
    scan_c<<<SCAN_B, 256, 0, stream>>>(degp, degt, boff, row_start, csr_sn);  // + fused pad fill
    scatter_kernel<<<(N_EDGES + 255) / 256, 256, 0, stream>>>(src, dst, pos, row_start,
                                                              sb4, dinv, csr_sn);

    wsplit_all<<<(196608 + 255) / 256, 256, 0, stream>>>(
        W_in, W_h1, W_h2, W_out,
        Whi_in, Wlo_in, Whi_h1, Wlo_h1, Whi_h2, Wlo_h2, Whi_out, Wlo_out);

    const int gemm_grid = (N_NODES + 63) / 64;
    const int agg_grid = (N_NODES + 3) / 4;

    // ---- Layer 1: gather emb (bf16, 128), agg at 128 (split out), GEMM 128->256 +b+relu (split out) ----
    gather_bf16<<<(N_NODES * (EMB_D / 4) + 255) / 256, 256, 0, stream>>>(node_ids, embed, E16);
    agg_node<128, unsigned short, false, false, false, true><<<agg_grid, 256, 0, stream>>>(
        row_start, csr_sn, dinv, E16, nullptr, nullptr, A1hi, A1lo);
    gemm_mfma<128, 256, true, true, 1><<<gemm_grid, 256, 0, stream>>>(
        A1hi, A1lo, Whi_in, Wlo_in, b_in, nullptr, Xhi, Xlo, N_NODES);

    // ---- Layer 2: GEMM 256->256 (fp8 out), fused agg+self+bias+residual+relu (split out) ----
    gemm_mfma<256, 256, false, false, 2><<<gemm_grid, 256, 0, stream>>>(
        Xhi, Xlo, Whi_h1, Wlo_h1, nullptr, H8, nullptr, nullptr, N_NODES);
    agg_node<256, unsigned char, true, true, true, true><<<agg_grid, 256, 0, stream>>>(
        row_start, csr_sn, dinv, H8, b_h1, nullptr, Xhi, Xlo);

    // ---- Layer 3: same ----
    gemm_mfma<256, 256, false, false, 2><<<gemm_grid, 256, 0, stream>>>(
        Xhi, Xlo, Whi_h2, Wlo_h2, nullptr, H8, nullptr, nullptr, N_NODES);
    agg_node<256, unsigned char, true, true, true, true><<<agg_grid, 256, 0, stream>>>(
        row_start, csr_sn, dinv, H8, b_h2, nullptr, Xhi, Xlo);

    // ---- Layer 4: GEMM 256->128 (fp8 out), agg at 128 +bias -> fp32 ----
    gemm_mfma<256, 128, false, false, 2><<<gemm_grid, 256, 0, stream>>>(
        Xhi, Xlo, Whi_out, Wlo_out, nullptr, H8_4, nullptr, nullptr, N_NODES);
    agg_node<128, unsigned char, true, false, false, false><<<agg_grid, 256, 0, stream>>>(
        row_start, csr_sn, dinv, H8_4, b_out, A1, nullptr, nullptr);

    // ---- readout: atomic-free per-graph mean (batch sorted) ----
    graph_mean<<<NGRAPH, 256, 0, stream>>>(bstart, A1, out);
}

// Round 16
// 424.738 us; speedup vs baseline: 1.3986x; 1.1187x over previous
//
#include <hip/hip_runtime.h>
#include <hip/hip_bf16.h>
#include <hip/hip_fp8.h>

#define N_NODES 50000
#define N_EDGES 800000
#define EMB_D 128
#define HID_D 256
#define OUT_D 128
#define NGRAPH 256

#define SCAN_B ((N_NODES + 256) / 256)   // 196 blocks covers N_NODES+1 slots
#define MAX_CSR (N_EDGES + 7 * N_NODES)  // pad-8 row capacity

typedef __attribute__((ext_vector_type(8))) short short8;
typedef __attribute__((ext_vector_type(4))) float floatx4;
typedef __attribute__((ext_vector_type(4))) unsigned short ushortx4;
typedef __attribute__((ext_vector_type(8))) unsigned short ushortx8;
typedef __attribute__((ext_vector_type(4))) unsigned char ucharx4;
typedef __attribute__((ext_vector_type(8))) unsigned char ucharx8;

__device__ inline unsigned short f2b(float f) {
    __hip_bfloat16 h = __float2bfloat16(f);
    return *reinterpret_cast<unsigned short*>(&h);
}

__device__ inline float b2f(unsigned short u) {
    union { unsigned int i; float f; } c;
    c.i = ((unsigned int)u) << 16;
    return c.f;
}

__device__ inline unsigned char f2f8(float f) {
    __hip_fp8_e4m3 v(f);                      // OCP e4m3 (gfx950 HW cvt)
    return (unsigned char)v.__x;
}

// message-operand element -> float (overloaded on storage type)
__device__ inline float h2f(unsigned short u) { return b2f(u); }
__device__ inline float h2f(unsigned char u) {
    __hip_fp8_e4m3 v; v.__x = (__hip_fp8_storage_t)u;
    return (float)v;
}

template<int D, typename HT> struct HVec;
template<> struct HVec<128, unsigned short> { using T = ushortx4; };  // 8B/lane
template<> struct HVec<256, unsigned short> { using T = ushortx8; };  // 16B/lane
template<> struct HVec<128, unsigned char>  { using T = ucharx4;  };  // 4B/lane
template<> struct HVec<256, unsigned char>  { using T = ucharx8;  };  // 8B/lane

// ---------------- rank pass: 4-shard degree histogram + per-edge rank ----------------
__global__ void rank_kernel(const int* __restrict__ dst, int* __restrict__ deg4,
                            int* __restrict__ pos) {
    int e = blockIdx.x * blockDim.x + threadIdx.x;
    if (e >= N_EDGES) return;
    pos[e] = atomicAdd(&deg4[(size_t)(e & 3) * N_NODES + dst[e]], 1);
}

// ---------------- scan phase A: merge shards, block sums (PAD-8), dinv, shard bases ----
__global__ void scan_a(const int* __restrict__ deg4, int* __restrict__ degt,
                       int* __restrict__ degp, int* __restrict__ sb4,
                       int* __restrict__ bsum, float* __restrict__ dinv) {
    __shared__ int red[256];
    int t = threadIdx.x;
    int i = blockIdx.x * 256 + t;
    int pad = 0;
    if (i < N_NODES) {
        int d0 = deg4[i];
        int d1 = deg4[(size_t)N_NODES + i];
        int d2 = deg4[(size_t)2 * N_NODES + i];
        int d3 = deg4[(size_t)3 * N_NODES + i];
        int tot = d0 + d1 + d2 + d3;
        degt[i] = tot;
        pad = (tot + 7) & ~7;            // row padded to multiple of 8
        degp[i] = pad;
        dinv[i] = rsqrtf((float)tot + 1.0f);
        sb4[i] = 0;
        sb4[(size_t)N_NODES + i] = d0;
        sb4[(size_t)2 * N_NODES + i] = d0 + d1;
        sb4[(size_t)3 * N_NODES + i] = d0 + d1 + d2;
    }
    red[t] = pad;
    __syncthreads();
    for (int off = 128; off > 0; off >>= 1) {
        if (t < off) red[t] += red[t + off];
        __syncthreads();
    }
    if (t == 0) bsum[blockIdx.x] = red[0];
}

// ---------------- phase B: exclusive scan of block sums + graph boundaries (1 block) ----
__global__ void scan_b(const int* __restrict__ bsum, int* __restrict__ boff,
                       const int* __restrict__ batch, int* __restrict__ bstart) {
    int t = threadIdx.x;
    {
        int lo = 0, hi = N_NODES;
        while (lo < hi) {
            int mid = (lo + hi) >> 1;
            if (batch[mid] < t) lo = mid + 1;
            else hi = mid;
        }
        bstart[t] = lo;
        if (t == 0) bstart[NGRAPH] = N_NODES;
    }
    __shared__ int s[256];
    s[t] = (t < SCAN_B) ? bsum[t] : 0;
    __syncthreads();
    for (int off = 1; off < 256; off <<= 1) {
        int v = (t >= off) ? s[t - off] : 0;
        __syncthreads();
        s[t] += v;
        __syncthreads();
    }
    if (t < SCAN_B) boff[t] = (t == 0) ? 0 : s[t - 1];
}

// ---------------- phase C: in-block scan -> row_start (padded) + fused sentinel fill ----
__global__ void scan_c(const int* __restrict__ degp, const int* __restrict__ degt,
                       const int* __restrict__ boff, int* __restrict__ row_start,
                       int2* __restrict__ csr_sn) {
    __shared__ int s[256];
    int t = threadIdx.x;
    int i = blockIdx.x * 256 + t;
    int v = (i < N_NODES) ? degp[i] : 0;
    s[t] = v;
    __syncthreads();
    for (int off = 1; off < 256; off <<= 1) {
        int x = (t >= off) ? s[t - off] : 0;
        __syncthreads();
        s[t] += x;
        __syncthreads();
    }
    int excl = s[t] - v;
    int rs = boff[blockIdx.x] + excl;
    if (i <= N_NODES) row_start[i] = rs;
    if (i < N_NODES) {
        int e_true = rs + degt[i];
        int e_end  = rs + degp[i];
        for (int k = e_true; k < e_end; ++k) csr_sn[k] = make_int2(0, 0);
    }
}

// ---------------- atomic-free CSR scatter (packed src+norm) ----------------
__global__ void scatter_kernel(const int* __restrict__ src, const int* __restrict__ dst,
                               const int* __restrict__ pos, const int* __restrict__ row_start,
                               const int* __restrict__ sb4, const float* __restrict__ dinv,
                               int2* __restrict__ csr_sn) {
    int e = blockIdx.x * blockDim.x + threadIdx.x;
    if (e >= N_EDGES) return;
    int s = src[e], d = dst[e];
    int slot = row_start[d] + sb4[(size_t)(e & 3) * N_NODES + d] + pos[e];
    csr_sn[slot] = make_int2(s, __float_as_int(dinv[s] * dinv[d]));
}

// ---------------- embedding gather -> bf16 rows ----------------
__global__ void gather_bf16(const int* __restrict__ ids, const float* __restrict__ embed,
                            unsigned short* __restrict__ X0) {
    int idx = blockIdx.x * blockDim.x + threadIdx.x;  // one float4 each
    const int V = EMB_D / 4;
    if (idx >= N_NODES * V) return;
    int row = idx / V, c = idx % V;
    float4 v = ((const float4*)embed)[(size_t)ids[row] * V + c];
    ushortx4 u;
    u[0] = f2b(v.x); u[1] = f2b(v.y); u[2] = f2b(v.z); u[3] = f2b(v.w);
    ((ushortx4*)X0)[idx] = u;
}

// ---------------- fused aggregation: one wave per node, two edges per wave ------------
// Rows padded to multiples of 8 (s=0,n=0 sentinels) -> single uniform loop.
// HT = unsigned short (bf16) or unsigned char (OCP fp8 e4m3) message operand.
// BOUT: write result as single bf16 ROW-MAJOR plane (GEMM A input);
// RES: residual read from the same bf16 plane.
template<int D, typename HT, bool HASB, bool RES, bool RELU, bool BOUT>
__global__ __launch_bounds__(256) void agg_node(
        const int* __restrict__ row_start, const int2* __restrict__ csr_sn,
        const float* __restrict__ dinv, const HT* __restrict__ H,
        const float* __restrict__ b, float* __restrict__ OUTF,
        unsigned short* __restrict__ Pb) {
    constexpr int V2 = D / 32;
    using UV = typename HVec<D, HT>::T;
    using RV = typename HVec<D, unsigned short>::T;
    int wave = threadIdx.x >> 6, lane = threadIdx.x & 63;
    int i = blockIdx.x * 4 + wave;
    if (i >= N_NODES) return;
    int h = lane >> 5, q = lane & 31;
    const int off = q * V2;
    const HT* __restrict__ Hoff = H + off;
    float acc0[V2], acc1[V2];
#pragma unroll
    for (int v = 0; v < V2; ++v) { acc0[v] = 0.f; acc1[v] = 0.f; }
    int e0 = row_start[i], e1 = row_start[i + 1];
    if (e0 < e1) {
        int2 sn0 = csr_sn[e0 + h];
        int2 sn1 = csr_sn[e0 + 2 + h];
        int2 sn2 = csr_sn[e0 + 4 + h];
        int2 sn3 = csr_sn[e0 + 6 + h];
        int e = e0 + 8;
        for (;;) {
            UV u0 = *(const UV*)(Hoff + (size_t)sn0.x * D);
            UV u1 = *(const UV*)(Hoff + (size_t)sn1.x * D);
            UV u2 = *(const UV*)(Hoff + (size_t)sn2.x * D);
            UV u3 = *(const UV*)(Hoff + (size_t)sn3.x * D);
            float n0 = __int_as_float(sn0.y), n1 = __int_as_float(sn1.y);
            float n2 = __int_as_float(sn2.y), n3 = __int_as_float(sn3.y);
            bool more = (e < e1);
            int2 t0, t1, t2, t3;
            if (more) {
                t0 = csr_sn[e + h];
                t1 = csr_sn[e + 2 + h];
                t2 = csr_sn[e + 4 + h];
                t3 = csr_sn[e + 6 + h];
            }
#pragma unroll
            for (int v = 0; v < V2; ++v) acc0[v] = fmaf(h2f(u0[v]), n0, acc0[v]);
#pragma unroll
            for (int v = 0; v < V2; ++v) acc1[v] = fmaf(h2f(u1[v]), n1, acc1[v]);
#pragma unroll
            for (int v = 0; v < V2; ++v) acc0[v] = fmaf(h2f(u2[v]), n2, acc0[v]);
#pragma unroll
            for (int v = 0; v < V2; ++v) acc1[v] = fmaf(h2f(u3[v]), n3, acc1[v]);
            if (!more) break;
            sn0 = t0; sn1 = t1; sn2 = t2; sn3 = t3;
            e += 8;
        }
    }
#pragma unroll
    for (int v = 0; v < V2; ++v) {
        float s = acc0[v] + acc1[v];
        acc0[v] = s + __shfl_xor(s, 32);
    }
    if (h == 0) {
        float di = dinv[i];
        float d2 = di * di;
        UV us = *(const UV*)(Hoff + (size_t)i * D);
        RV rb;
        if (RES) rb = *(const RV*)(Pb + (size_t)i * D + off);
        RV ob;
#pragma unroll
        for (int v = 0; v < V2; ++v) {
            float val = acc0[v];
            val = fmaf(h2f(us[v]), d2, val);
            if (HASB) val += b[off + v];
            if (RES)  val += b2f(rb[v]);
            if (RELU) val = fmaxf(val, 0.f);
            if (BOUT) ob[v] = f2b(val);
            else      OUTF[(size_t)i * D + off + v] = val;
        }
        if (BOUT) *(RV*)(Pb + (size_t)i * D + off) = ob;
    }
}

// ---------------- W -> B-fragment-major single bf16 (all 4 weights, 1 launch) ----------
template<int K, int D>
__device__ inline void wsplit_one(int idx, const float* __restrict__ W,
                                  short* __restrict__ wb) {
    int j = idx & 7;
    int l = (idx >> 3) & 63;
    int rest = idx >> 9;
    int kb = rest % (K / 32);
    int t = rest / (K / 32);
    int k = kb * 32 + (l >> 4) * 8 + j;
    int ncol = t * 16 + (l & 15);
    wb[idx] = (short)f2b(W[(size_t)k * D + ncol]);
}

__global__ void wsplit_all(const float* __restrict__ W_in, const float* __restrict__ W_h1,
                           const float* __restrict__ W_h2, const float* __restrict__ W_out,
                           short* __restrict__ wb_in, short* __restrict__ wb_h1,
                           short* __restrict__ wb_h2, short* __restrict__ wb_out) {
    int idx = blockIdx.x * blockDim.x + threadIdx.x;
    constexpr int S1 = EMB_D * HID_D;          // 32768
    constexpr int S2 = S1 + HID_D * HID_D;     // 98304
    constexpr int S3 = S2 + HID_D * HID_D;     // 163840
    constexpr int S4 = S3 + HID_D * OUT_D;     // 196608
    if (idx < S1)      wsplit_one<EMB_D, HID_D>(idx,      W_in,  wb_in);
    else if (idx < S2) wsplit_one<HID_D, HID_D>(idx - S1, W_h1,  wb_h1);
    else if (idx < S3) wsplit_one<HID_D, HID_D>(idx - S2, W_h2,  wb_h2);
    else if (idx < S4) wsplit_one<HID_D, OUT_D>(idx - S3, W_out, wb_out);
}

// ---------------- MFMA GEMM: Hout[N,D] = A[N,K] @ W[K,D] (+bias)(+relu) ----------------
// Single-bf16 A (row-major plane) and W (fragment-major). ONE MFMA per tile per kb.
// OMODE: 0 = bf16 out, 2 = fp8 e4m3 out (message operand).
template<int K, int D, bool BIAS, bool RELU, int OMODE>
__global__ __launch_bounds__(256) void gemm_mfma(
        const unsigned short* __restrict__ A_g, const short* __restrict__ Wb,
        const float* __restrict__ b, void* __restrict__ OutB, int n) {
    constexpr int LDK = K + 8;
    constexpr int NT = D / 64;
    constexpr int KB = K / 32;
    __shared__ __align__(16) short Ab[64 * LDK];

    int row0 = blockIdx.x * 64;
    constexpr int NF8 = 64 * (K / 8);
    for (int idx = threadIdx.x; idx < NF8; idx += 256) {
        int r = idx / (K / 8), c8 = idx % (K / 8);
        ushortx8 vh = {0, 0, 0, 0, 0, 0, 0, 0};
        if (row0 + r < n)
            vh = *(const ushortx8*)(A_g + (size_t)(row0 + r) * K + c8 * 8);
        *(ushortx8*)&Ab[r * LDK + c8 * 8] = vh;
    }
    __syncthreads();

    int wave = threadIdx.x >> 6, lane = threadIdx.x & 63;
    int quad = lane >> 4, lane15 = lane & 15;

    floatx4 acc[4][NT];
#pragma unroll
    for (int mt = 0; mt < 4; ++mt)
#pragma unroll
        for (int nt = 0; nt < NT; ++nt)
            acc[mt][nt] = (floatx4){0.f, 0.f, 0.f, 0.f};

#pragma unroll
    for (int kb = 0; kb < KB; ++kb) {
        short8 ah[4];
#pragma unroll
        for (int mt = 0; mt < 4; ++mt) {
            int addr = (mt * 16 + lane15) * LDK + kb * 32 + quad * 8;
            ah[mt] = *(const short8*)&Ab[addr];
        }
        short8 bh[NT];
#pragma unroll
        for (int nt = 0; nt < NT; ++nt) {
            int t = wave * NT + nt;
            size_t fb = ((size_t)(t * KB + kb) * 64 + lane) * 8;
            bh[nt] = *(const short8*)&Wb[fb];
        }
#pragma unroll
        for (int mt = 0; mt < 4; ++mt)
#pragma unroll
            for (int nt = 0; nt < NT; ++nt)
                acc[mt][nt] = __builtin_amdgcn_mfma_f32_16x16x32_bf16(ah[mt], bh[nt], acc[mt][nt], 0, 0, 0);
    }

#pragma unroll
    for (int mt = 0; mt < 4; ++mt) {
#pragma unroll
        for (int nt = 0; nt < NT; ++nt) {
            int col = wave * (NT * 16) + nt * 16 + lane15;
            float bj = BIAS ? b[col] : 0.f;
#pragma unroll
            for (int reg = 0; reg < 4; ++reg) {
                int row = row0 + mt * 16 + quad * 4 + reg;
                if (row < n) {
                    float v = acc[mt][nt][reg] + bj;
                    if (RELU) v = fmaxf(v, 0.f);
                    if (OMODE == 2) ((unsigned char*)OutB)[(size_t)row * D + col] = f2f8(v);
                    else            ((unsigned short*)OutB)[(size_t)row * D + col] = f2b(v);
                }
            }
        }
    }
}

// ---------------- readout: one block per graph, atomic-free mean ----------------
__global__ void graph_mean(const int* __restrict__ bstart, const float* __restrict__ X,
                           float* __restrict__ out) {
    int g = blockIdx.x;
    int r0 = bstart[g], r1 = bstart[g + 1];
    int col = threadIdx.x & 127, rr = threadIdx.x >> 7;  // 2 rows in flight
    float acc = 0.f;
    for (int r = r0 + rr; r < r1; r += 2)
        acc += X[(size_t)r * OUT_D + col];
    __shared__ float sh[128];
    if (rr == 1) sh[col] = acc;
    __syncthreads();
    if (rr == 0) {
        float tot = acc + sh[col];
        int c = r1 - r0;
        out[(size_t)g * OUT_D + col] = tot / (float)(c > 0 ? c : 1);
    }
}

extern "C" void kernel_launch(void* const* d_in, const int* in_sizes, int n_in,
                              void* d_out, int out_size, void* d_ws, size_t ws_size,
                              hipStream_t stream) {
    const int* node_ids = (const int*)d_in[0];
    const int* edge_index = (const int*)d_in[1];
    const int* batch = (const int*)d_in[2];
    const float* embed = (const float*)d_in[3];
    const float* W_in  = (const float*)d_in[4];
    const float* b_in  = (const float*)d_in[5];
    const float* W_h1  = (const float*)d_in[6];
    const float* b_h1  = (const float*)d_in[7];
    const float* W_h2  = (const float*)d_in[8];
    const float* b_h2  = (const float*)d_in[9];
    const float* W_out = (const float*)d_in[10];
    const float* b_out = (const float*)d_in[11];
    float* out = (float*)d_out;

    const int* src = edge_index;
    const int* dst = edge_index + N_EDGES;

    char* w = (char*)d_ws;
    size_t o = 0;
    auto alloc = [&](size_t bytes) -> void* {
        void* p = w + o;
        o = (o + bytes + 255) & ~(size_t)255;
        return p;
    };
    int*   deg4     = (int*)alloc((size_t)4 * N_NODES * sizeof(int));
    int*   sb4      = (int*)alloc((size_t)4 * N_NODES * sizeof(int));
    int*   degt     = (int*)alloc((size_t)N_NODES * sizeof(int));
    int*   degp     = (int*)alloc((size_t)N_NODES * sizeof(int));
    int*   pos      = (int*)alloc((size_t)N_EDGES * sizeof(int));
    float* dinv     = (float*)alloc((size_t)N_NODES * sizeof(float));
    int*   bstart   = (int*)alloc((size_t)(NGRAPH + 1) * sizeof(int));
    int*   row_start= (int*)alloc((size_t)(N_NODES + 1) * sizeof(int));
    int*   bsum     = (int*)alloc((size_t)SCAN_B * sizeof(int));
    int*   boff     = (int*)alloc((size_t)SCAN_B * sizeof(int));
    int2*  csr_sn   = (int2*)alloc((size_t)MAX_CSR * sizeof(int2));
    unsigned short* Xb  = (unsigned short*)alloc((size_t)N_NODES * HID_D * sizeof(short)); // bf16 X (residual + GEMM A)
    unsigned short* E16 = (unsigned short*)alloc((size_t)N_NODES * EMB_D * sizeof(short)); // bf16 layer-1 operand
    unsigned char*  H8  = (unsigned char*)alloc((size_t)N_NODES * HID_D);                  // fp8 message operand (layers 2-4)
    unsigned short* A1b = (unsigned short*)alloc((size_t)N_NODES * 128 * sizeof(short));   // bf16 layer-1 agg out
    float* A1       = (float*)alloc((size_t)N_NODES * 128 * sizeof(float));                // final agg out (fp32)
    short* Wb_in    = (short*)alloc((size_t)EMB_D * HID_D * sizeof(short));
    short* Wb_h1    = (short*)alloc((size_t)HID_D * HID_D * sizeof(short));
    short* Wb_h2    = (short*)alloc((size_t)HID_D * HID_D * sizeof(short));
    short* Wb_out   = (short*)alloc((size_t)HID_D * OUT_D * sizeof(short));
    unsigned char* H8_4 = H8;                // layer-4 fp8 GEMM out [N,128] alias
    (void)ws_size;

    hipMemsetAsync(deg4, 0, (size_t)4 * N_NODES * sizeof(int), stream);

    rank_kernel<<<(N_EDGES + 255) / 256, 256, 0, stream>>>(dst, deg4, pos);
    scan_a<<<SCAN_B, 256, 0, stream>>>(deg4, degt, degp, sb4, bsum, dinv);
    scan_b<<<1, 256, 0, stream>>>(bsum, boff, batch, bstart);   // + fused graph boundaries
    scan_c<<<SCAN_B, 256, 0, stream>>>(degp, degt, boff, row_start, csr_sn);  // + fused pad fill
    scatter_kernel<<<(N_EDGES + 255) / 256, 256, 0, stream>>>(src, dst, pos, row_start,
                                                              sb4, dinv, csr_sn);

    wsplit_all<<<(196608 + 255) / 256, 256, 0, stream>>>(
        W_in, W_h1, W_h2, W_out, Wb_in, Wb_h1, Wb_h2, Wb_out);

    const int gemm_grid = (N_NODES + 63) / 64;
    const int agg_grid = (N_NODES + 3) / 4;

    // ---- Layer 1: gather emb (bf16, 128), agg at 128 (bf16 out), GEMM 128->256 +b+relu (bf16 out) ----
    gather_bf16<<<(N_NODES * (EMB_D / 4) + 255) / 256, 256, 0, stream>>>(node_ids, embed, E16);
    agg_node<128, unsigned short, false, false, false, true><<<agg_grid, 256, 0, stream>>>(
        row_start, csr_sn, dinv, E16, nullptr, nullptr, A1b);
    gemm_mfma<128, 256, true, true, 0><<<gemm_grid, 256, 0, stream>>>(
        A1b, Wb_in, b_in, Xb, N_NODES);

    // ---- Layer 2: GEMM 256->256 (fp8 out), fused agg+self+bias+residual+relu (bf16 out) ----
    gemm_mfma<256, 256, false, false, 2><<<gemm_grid, 256, 0, stream>>>(
        Xb, Wb_h1, nullptr, H8, N_NODES);
    agg_node<256, unsigned char, true, true, true, true><<<agg_grid, 256, 0, stream>>>(
        row_start, csr_sn, dinv, H8, b_h1, nullptr, Xb);

    // ---- Layer 3: same ----
    gemm_mfma<256, 256, false, false, 2><<<gemm_grid, 256, 0, stream>>>(
        Xb, Wb_h2, nullptr, H8, N_NODES);
    agg_node<256, unsigned char, true, true, true, true><<<agg_grid, 256, 0, stream>>>(
        row_start, csr_sn, dinv, H8, b_h2, nullptr, Xb);

    // ---- Layer 4: GEMM 256->128 (fp8 out), agg at 128 +bias -> fp32 ----
    gemm_mfma<256, 128, false, false, 2><<<gemm_grid, 256, 0, stream>>>(
        Xb, Wb_out, nullptr, H8_4, N_NODES);
    agg_node<128, unsigned char, true, false, false, false><<<agg_grid, 256, 0, stream>>>(
        row_start, csr_sn, dinv, H8_4, b_out, A1, nullptr);

    // ---- readout: atomic-free per-graph mean (batch sorted) ----
    graph_mean<<<NGRAPH, 256, 0, stream>>>(bstart, A1, out);
}

// Round 17
// 395.677 us; speedup vs baseline: 1.5013x; 1.0734x over previous
//
#include <hip/hip_runtime.h>
#include <hip/hip_bf16.h>
#include <hip/hip_fp8.h>

#define N_NODES 50000
#define N_EDGES 800000
#define EMB_D 128
#define HID_D 256
#define OUT_D 128
#define NGRAPH 256

#define SCAN_B ((N_NODES + 256) / 256)   // 196 blocks covers N_NODES+1 slots
#define MAX_CSR (N_EDGES + 7 * N_NODES)  // pad-8 row capacity

typedef __attribute__((ext_vector_type(8))) short short8;
typedef __attribute__((ext_vector_type(4))) float floatx4;
typedef __attribute__((ext_vector_type(4))) unsigned short ushortx4;
typedef __attribute__((ext_vector_type(8))) unsigned short ushortx8;
typedef __attribute__((ext_vector_type(4))) unsigned char ucharx4;
typedef __attribute__((ext_vector_type(8))) unsigned char ucharx8;

__device__ inline unsigned short f2b(float f) {
    __hip_bfloat16 h = __float2bfloat16(f);
    return *reinterpret_cast<unsigned short*>(&h);
}

__device__ inline float b2f(unsigned short u) {
    union { unsigned int i; float f; } c;
    c.i = ((unsigned int)u) << 16;
    return c.f;
}

__device__ inline unsigned char f2f8(float f) {
    __hip_fp8_e4m3 v(f);                      // OCP e4m3 (gfx950 HW cvt)
    return (unsigned char)v.__x;
}

// message-operand element -> float (overloaded on storage type)
__device__ inline float h2f(unsigned short u) { return b2f(u); }
__device__ inline float h2f(unsigned char u) {
    __hip_fp8_e4m3 v; v.__x = (__hip_fp8_storage_t)u;
    return (float)v;
}

template<int D, typename HT> struct HVec;
template<> struct HVec<128, unsigned short> { using T = ushortx4; };  // 8B/lane
template<> struct HVec<256, unsigned short> { using T = ushortx8; };  // 16B/lane
template<> struct HVec<128, unsigned char>  { using T = ucharx4;  };  // 4B/lane
template<> struct HVec<256, unsigned char>  { using T = ucharx8;  };  // 8B/lane

// ---------------- rank pass: 4-shard degree histogram + per-edge rank ----------------
__global__ void rank_kernel(const int* __restrict__ dst, int* __restrict__ deg4,
                            int* __restrict__ pos) {
    int e = blockIdx.x * blockDim.x + threadIdx.x;
    if (e >= N_EDGES) return;
    pos[e] = atomicAdd(&deg4[(size_t)(e & 3) * N_NODES + dst[e]], 1);
}

// ---------------- scan phase A: merge shards, block sums (PAD-8), dinv, shard bases ----
__global__ void scan_a(const int* __restrict__ deg4, int* __restrict__ degt,
                       int* __restrict__ degp, int* __restrict__ sb4,
                       int* __restrict__ bsum, float* __restrict__ dinv) {
    __shared__ int red[256];
    int t = threadIdx.x;
    int i = blockIdx.x * 256 + t;
    int pad = 0;
    if (i < N_NODES) {
        int d0 = deg4[i];
        int d1 = deg4[(size_t)N_NODES + i];
        int d2 = deg4[(size_t)2 * N_NODES + i];
        int d3 = deg4[(size_t)3 * N_NODES + i];
        int tot = d0 + d1 + d2 + d3;
        degt[i] = tot;
        pad = (tot + 7) & ~7;            // row padded to multiple of 8
        degp[i] = pad;
        dinv[i] = rsqrtf((float)tot + 1.0f);
        sb4[i] = 0;
        sb4[(size_t)N_NODES + i] = d0;
        sb4[(size_t)2 * N_NODES + i] = d0 + d1;
        sb4[(size_t)3 * N_NODES + i] = d0 + d1 + d2;
    }
    red[t] = pad;
    __syncthreads();
    for (int off = 128; off > 0; off >>= 1) {
        if (t < off) red[t] += red[t + off];
        __syncthreads();
    }
    if (t == 0) bsum[blockIdx.x] = red[0];
}

// ---------------- phase B: exclusive scan of block sums + graph boundaries (1 block) ----
__global__ void scan_b(const int* __restrict__ bsum, int* __restrict__ boff,
                       const int* __restrict__ batch, int* __restrict__ bstart) {
    int t = threadIdx.x;
    {
        int lo = 0, hi = N_NODES;
        while (lo < hi) {
            int mid = (lo + hi) >> 1;
            if (batch[mid] < t) lo = mid + 1;
            else hi = mid;
        }
        bstart[t] = lo;
        if (t == 0) bstart[NGRAPH] = N_NODES;
    }
    __shared__ int s[256];
    s[t] = (t < SCAN_B) ? bsum[t] : 0;
    __syncthreads();
    for (int off = 1; off < 256; off <<= 1) {
        int v = (t >= off) ? s[t - off] : 0;
        __syncthreads();
        s[t] += v;
        __syncthreads();
    }
    if (t < SCAN_B) boff[t] = (t == 0) ? 0 : s[t - 1];
}

// ---------------- phase C: in-block scan -> row_start (padded) + fused sentinel fill ----
__global__ void scan_c(const int* __restrict__ degp, const int* __restrict__ degt,
                       const int* __restrict__ boff, int* __restrict__ row_start,
                       unsigned int* __restrict__ csr) {
    __shared__ int s[256];
    int t = threadIdx.x;
    int i = blockIdx.x * 256 + t;
    int v = (i < N_NODES) ? degp[i] : 0;
    s[t] = v;
    __syncthreads();
    for (int off = 1; off < 256; off <<= 1) {
        int x = (t >= off) ? s[t - off] : 0;
        __syncthreads();
        s[t] += x;
        __syncthreads();
    }
    int excl = s[t] - v;
    int rs = boff[blockIdx.x] + excl;
    if (i <= N_NODES) row_start[i] = rs;
    if (i < N_NODES) {
        int e_true = rs + degt[i];
        int e_end  = rs + degp[i];
        for (int k = e_true; k < e_end; ++k) csr[k] = 0u;   // src=0, norm=0
    }
}

// ---------------- atomic-free CSR scatter (u16 src | bf16 norm packed in u32) ----------
__global__ void scatter_kernel(const int* __restrict__ src, const int* __restrict__ dst,
                               const int* __restrict__ pos, const int* __restrict__ row_start,
                               const int* __restrict__ sb4, const float* __restrict__ dinv,
                               unsigned int* __restrict__ csr) {
    int e = blockIdx.x * blockDim.x + threadIdx.x;
    if (e >= N_EDGES) return;
    int s = src[e], d = dst[e];
    int slot = row_start[d] + sb4[(size_t)(e & 3) * N_NODES + d] + pos[e];
    csr[slot] = ((unsigned int)f2b(dinv[s] * dinv[d]) << 16) | (unsigned int)s;
}

// ---------------- prep: embedding gather -> fp8 rows + W -> fragment-major bf16 --------
template<int K, int D>
__device__ inline void wsplit_one(int idx, const float* __restrict__ W,
                                  short* __restrict__ wb) {
    int j = idx & 7;
    int l = (idx >> 3) & 63;
    int rest = idx >> 9;
    int kb = rest % (K / 32);
    int t = rest / (K / 32);
    int k = kb * 32 + (l >> 4) * 8 + j;
    int ncol = t * 16 + (l & 15);
    wb[idx] = (short)f2b(W[(size_t)k * D + ncol]);
}

__global__ void prep_kernel(const int* __restrict__ ids, const float* __restrict__ embed,
                            unsigned char* __restrict__ E8,
                            const float* __restrict__ W_in, const float* __restrict__ W_h1,
                            const float* __restrict__ W_h2, const float* __restrict__ W_out,
                            short* __restrict__ wb_in, short* __restrict__ wb_h1,
                            short* __restrict__ wb_h2, short* __restrict__ wb_out) {
    int idx = blockIdx.x * blockDim.x + threadIdx.x;
    constexpr int GV = N_NODES * (EMB_D / 4);  // 1.6M float4->fp8x4 gathers
    if (idx < GV) {
        const int V = EMB_D / 4;
        int row = idx / V, c = idx % V;
        float4 v = ((const float4*)embed)[(size_t)ids[row] * V + c];
        ucharx4 u;
        u[0] = f2f8(v.x); u[1] = f2f8(v.y); u[2] = f2f8(v.z); u[3] = f2f8(v.w);
        ((ucharx4*)E8)[idx] = u;
        return;
    }
    int j = idx - GV;
    constexpr int S1 = EMB_D * HID_D;          // 32768
    constexpr int S2 = S1 + HID_D * HID_D;     // 98304
    constexpr int S3 = S2 + HID_D * HID_D;     // 163840
    constexpr int S4 = S3 + HID_D * OUT_D;     // 196608
    if (j < S1)      wsplit_one<EMB_D, HID_D>(j,      W_in,  wb_in);
    else if (j < S2) wsplit_one<HID_D, HID_D>(j - S1, W_h1,  wb_h1);
    else if (j < S3) wsplit_one<HID_D, HID_D>(j - S2, W_h2,  wb_h2);
    else if (j < S4) wsplit_one<HID_D, OUT_D>(j - S3, W_out, wb_out);
}

// ---------------- fused aggregation: one wave per node, two edges per wave ------------
// Rows padded to multiples of 8 (packed csr=0 sentinels) -> single uniform loop.
// HT = unsigned short (bf16) or unsigned char (OCP fp8 e4m3) message operand.
// BOUT: write result as single bf16 ROW-MAJOR plane (GEMM A input);
// RES: residual read from the same bf16 plane.
template<int D, typename HT, bool HASB, bool RES, bool RELU, bool BOUT>
__global__ __launch_bounds__(256) void agg_node(
        const int* __restrict__ row_start, const unsigned int* __restrict__ csr,
        const float* __restrict__ dinv, const HT* __restrict__ H,
        const float* __restrict__ b, float* __restrict__ OUTF,
        unsigned short* __restrict__ Pb) {
    constexpr int V2 = D / 32;
    using UV = typename HVec<D, HT>::T;
    using RV = typename HVec<D, unsigned short>::T;
    int wave = threadIdx.x >> 6, lane = threadIdx.x & 63;
    int i = blockIdx.x * 4 + wave;
    if (i >= N_NODES) return;
    int h = lane >> 5, q = lane & 31;
    const int off = q * V2;
    const HT* __restrict__ Hoff = H + off;
    float acc0[V2], acc1[V2];
#pragma unroll
    for (int v = 0; v < V2; ++v) { acc0[v] = 0.f; acc1[v] = 0.f; }
    int e0 = row_start[i], e1 = row_start[i + 1];
    if (e0 < e1) {
        unsigned int sn0 = csr[e0 + h];
        unsigned int sn1 = csr[e0 + 2 + h];
        unsigned int sn2 = csr[e0 + 4 + h];
        unsigned int sn3 = csr[e0 + 6 + h];
        int e = e0 + 8;
        for (;;) {
            UV u0 = *(const UV*)(Hoff + (size_t)(sn0 & 0xFFFFu) * D);
            UV u1 = *(const UV*)(Hoff + (size_t)(sn1 & 0xFFFFu) * D);
            UV u2 = *(const UV*)(Hoff + (size_t)(sn2 & 0xFFFFu) * D);
            UV u3 = *(const UV*)(Hoff + (size_t)(sn3 & 0xFFFFu) * D);
            float n0 = b2f((unsigned short)(sn0 >> 16));
            float n1 = b2f((unsigned short)(sn1 >> 16));
            float n2 = b2f((unsigned short)(sn2 >> 16));
            float n3 = b2f((unsigned short)(sn3 >> 16));
            bool more = (e < e1);
            unsigned int t0, t1, t2, t3;
            if (more) {
                t0 = csr[e + h];
                t1 = csr[e + 2 + h];
                t2 = csr[e + 4 + h];
                t3 = csr[e + 6 + h];
            }
#pragma unroll
            for (int v = 0; v < V2; ++v) acc0[v] = fmaf(h2f(u0[v]), n0, acc0[v]);
#pragma unroll
            for (int v = 0; v < V2; ++v) acc1[v] = fmaf(h2f(u1[v]), n1, acc1[v]);
#pragma unroll
            for (int v = 0; v < V2; ++v) acc0[v] = fmaf(h2f(u2[v]), n2, acc0[v]);
#pragma unroll
            for (int v = 0; v < V2; ++v) acc1[v] = fmaf(h2f(u3[v]), n3, acc1[v]);
            if (!more) break;
            sn0 = t0; sn1 = t1; sn2 = t2; sn3 = t3;
            e += 8;
        }
    }
#pragma unroll
    for (int v = 0; v < V2; ++v) {
        float s = acc0[v] + acc1[v];
        acc0[v] = s + __shfl_xor(s, 32);
    }
    if (h == 0) {
        float di = dinv[i];
        float d2 = di * di;
        UV us = *(const UV*)(Hoff + (size_t)i * D);
        RV rb;
        if (RES) rb = *(const RV*)(Pb + (size_t)i * D + off);
        RV ob;
#pragma unroll
        for (int v = 0; v < V2; ++v) {
            float val = acc0[v];
            val = fmaf(h2f(us[v]), d2, val);
            if (HASB) val += b[off + v];
            if (RES)  val += b2f(rb[v]);
            if (RELU) val = fmaxf(val, 0.f);
            if (BOUT) ob[v] = f2b(val);
            else      OUTF[(size_t)i * D + off + v] = val;
        }
        if (BOUT) *(RV*)(Pb + (size_t)i * D + off) = ob;
    }
}

// ---------------- MFMA GEMM: Hout[N,D] = A[N,K] @ W[K,D] (+bias)(+relu) ----------------
// Single-bf16 A (row-major plane) and W (fragment-major). ONE MFMA per tile per kb.
// OMODE: 0 = bf16 out, 2 = fp8 e4m3 out (message operand).
template<int K, int D, bool BIAS, bool RELU, int OMODE>
__global__ __launch_bounds__(256) void gemm_mfma(
        const unsigned short* __restrict__ A_g, const short* __restrict__ Wb,
        const float* __restrict__ b, void* __restrict__ OutB, int n) {
    constexpr int LDK = K + 8;
    constexpr int NT = D / 64;
    constexpr int KB = K / 32;
    __shared__ __align__(16) short Ab[64 * LDK];

    int row0 = blockIdx.x * 64;
    constexpr int NF8 = 64 * (K / 8);
    for (int idx = threadIdx.x; idx < NF8; idx += 256) {
        int r = idx / (K / 8), c8 = idx % (K / 8);
        ushortx8 vh = {0, 0, 0, 0, 0, 0, 0, 0};
        if (row0 + r < n)
            vh = *(const ushortx8*)(A_g + (size_t)(row0 + r) * K + c8 * 8);
        *(ushortx8*)&Ab[r * LDK + c8 * 8] = vh;
    }
    __syncthreads();

    int wave = threadIdx.x >> 6, lane = threadIdx.x & 63;
    int quad = lane >> 4, lane15 = lane & 15;

    floatx4 acc[4][NT];
#pragma unroll
    for (int mt = 0; mt < 4; ++mt)
#pragma unroll
        for (int nt = 0; nt < NT; ++nt)
            acc[mt][nt] = (floatx4){0.f, 0.f, 0.f, 0.f};

#pragma unroll
    for (int kb = 0; kb < KB; ++kb) {
        short8 ah[4];
#pragma unroll
        for (int mt = 0; mt < 4; ++mt) {
            int addr = (mt * 16 + lane15) * LDK + kb * 32 + quad * 8;
            ah[mt] = *(const short8*)&Ab[addr];
        }
        short8 bh[NT];
#pragma unroll
        for (int nt = 0; nt < NT; ++nt) {
            int t = wave * NT + nt;
            size_t fb = ((size_t)(t * KB + kb) * 64 + lane) * 8;
            bh[nt] = *(const short8*)&Wb[fb];
        }
#pragma unroll
        for (int mt = 0; mt < 4; ++mt)
#pragma unroll
            for (int nt = 0; nt < NT; ++nt)
                acc[mt][nt] = __builtin_amdgcn_mfma_f32_16x16x32_bf16(ah[mt], bh[nt], acc[mt][nt], 0, 0, 0);
    }

#pragma unroll
    for (int mt = 0; mt < 4; ++mt) {
#pragma unroll
        for (int nt = 0; nt < NT; ++nt) {
            int col = wave * (NT * 16) + nt * 16 + lane15;
            float bj = BIAS ? b[col] : 0.f;
#pragma unroll
            for (int reg = 0; reg < 4; ++reg) {
                int row = row0 + mt * 16 + quad * 4 + reg;
                if (row < n) {
                    float v = acc[mt][nt][reg] + bj;
                    if (RELU) v = fmaxf(v, 0.f);
                    if (OMODE == 2) ((unsigned char*)OutB)[(size_t)row * D + col] = f2f8(v);
                    else            ((unsigned short*)OutB)[(size_t)row * D + col] = f2b(v);
                }
            }
        }
    }
}

// ---------------- readout: one block per graph, atomic-free mean ----------------
__global__ void graph_mean(const int* __restrict__ bstart, const float* __restrict__ X,
                           float* __restrict__ out) {
    int g = blockIdx.x;
    int r0 = bstart[g], r1 = bstart[g + 1];
    int col = threadIdx.x & 127, rr = threadIdx.x >> 7;  // 2 rows in flight
    float acc = 0.f;
    for (int r = r0 + rr; r < r1; r += 2)
        acc += X[(size_t)r * OUT_D + col];
    __shared__ float sh[128];
    if (rr == 1) sh[col] = acc;
    __syncthreads();
    if (rr == 0) {
        float tot = acc + sh[col];
        int c = r1 - r0;
        out[(size_t)g * OUT_D + col] = tot / (float)(c > 0 ? c : 1);
    }
}

extern "C" void kernel_launch(void* const* d_in, const int* in_sizes, int n_in,
                              void* d_out, int out_size, void* d_ws, size_t ws_size,
                              hipStream_t stream) {
    const int* node_ids = (const int*)d_in[0];
    const int* edge_index = (const int*)d_in[1];
    const int* batch = (const int*)d_in[2];
    const float* embed = (const float*)d_in[3];
    const float* W_in  = (const float*)d_in[4];
    const float* b_in  = (const float*)d_in[5];
    const float* W_h1  = (const float*)d_in[6];
    const float* b_h1  = (const float*)d_in[7];
    const float* W_h2  = (const float*)d_in[8];
    const float* b_h2  = (const float*)d_in[9];
    const float* W_out = (const float*)d_in[10];
    const float* b_out = (const float*)d_in[11];
    float* out = (float*)d_out;

    const int* src = edge_index;
    const int* dst = edge_index + N_EDGES;

    char* w = (char*)d_ws;
    size_t o = 0;
    auto alloc = [&](size_t bytes) -> void* {
        void* p = w + o;
        o = (o + bytes + 255) & ~(size_t)255;
        return p;
    };
    int*   deg4     = (int*)alloc((size_t)4 * N_NODES * sizeof(int));
    int*   sb4      = (int*)alloc((size_t)4 * N_NODES * sizeof(int));
    int*   degt     = (int*)alloc((size_t)N_NODES * sizeof(int));
    int*   degp     = (int*)alloc((size_t)N_NODES * sizeof(int));
    int*   pos      = (int*)alloc((size_t)N_EDGES * sizeof(int));
    float* dinv     = (float*)alloc((size_t)N_NODES * sizeof(float));
    int*   bstart   = (int*)alloc((size_t)(NGRAPH + 1) * sizeof(int));
    int*   row_start= (int*)alloc((size_t)(N_NODES + 1) * sizeof(int));
    int*   bsum     = (int*)alloc((size_t)SCAN_B * sizeof(int));
    int*   boff     = (int*)alloc((size_t)SCAN_B * sizeof(int));
    unsigned int* csr = (unsigned int*)alloc((size_t)MAX_CSR * sizeof(unsigned int));
    unsigned short* Xb  = (unsigned short*)alloc((size_t)N_NODES * HID_D * sizeof(short)); // bf16 X (residual + GEMM A)
    unsigned char*  E8  = (unsigned char*)alloc((size_t)N_NODES * EMB_D);                  // fp8 layer-1 operand
    unsigned char*  H8  = (unsigned char*)alloc((size_t)N_NODES * HID_D);                  // fp8 message operand (layers 2-4)
    unsigned short* A1b = (unsigned short*)alloc((size_t)N_NODES * 128 * sizeof(short));   // bf16 layer-1 agg out
    float* A1       = (float*)alloc((size_t)N_NODES * 128 * sizeof(float));                // final agg out (fp32)
    short* Wb_in    = (short*)alloc((size_t)EMB_D * HID_D * sizeof(short));
    short* Wb_h1    = (short*)alloc((size_t)HID_D * HID_D * sizeof(short));
    short* Wb_h2    = (short*)alloc((size_t)HID_D * HID_D * sizeof(short));
    short* Wb_out   = (short*)alloc((size_t)HID_D * OUT_D * sizeof(short));
    unsigned char* H8_4 = H8;                // layer-4 fp8 GEMM out [N,128] alias
    (void)ws_size;

    hipMemsetAsync(deg4, 0, (size_t)4 * N_NODES * sizeof(int), stream);

    rank_kernel<<<(N_EDGES + 255) / 256, 256, 0, stream>>>(dst, deg4, pos);
    scan_a<<<SCAN_B, 256, 0, stream>>>(deg4, degt, degp, sb4, bsum, dinv);
    scan_b<<<1, 256, 0, stream>>>(bsum, boff, batch, bstart);   // + fused graph boundaries
    scan_c<<<SCAN_B, 256, 0, stream>>>(degp, degt, boff, row_start, csr);  // + fused pad fill
    scatter_kernel<<<(N_EDGES + 255) / 256, 256, 0, stream>>>(src, dst, pos, row_start,
                                                              sb4, dinv, csr);

    // fused: embedding gather (fp8) + all 4 weight repacks
    constexpr int GV = N_NODES * (EMB_D / 4);
    prep_kernel<<<(GV + 196608 + 255) / 256, 256, 0, stream>>>(
        node_ids, embed, E8, W_in, W_h1, W_h2, W_out, Wb_in, Wb_h1, Wb_h2, Wb_out);

    const int gemm_grid = (N_NODES + 63) / 64;
    const int agg_grid = (N_NODES + 3) / 4;

    // ---- Layer 1: agg fp8 emb at 128 (bf16 out), GEMM 128->256 +b+relu (bf16 out) ----
    agg_node<128, unsigned char, false, false, false, true><<<agg_grid, 256, 0, stream>>>(
        row_start, csr, dinv, E8, nullptr, nullptr, A1b);
    gemm_mfma<128, 256, true, true, 0><<<gemm_grid, 256, 0, stream>>>(
        A1b, Wb_in, b_in, Xb, N_NODES);

    // ---- Layer 2: GEMM 256->256 (fp8 out), fused agg+self+bias+residual+relu (bf16 out) ----
    gemm_mfma<256, 256, false, false, 2><<<gemm_grid, 256, 0, stream>>>(
        Xb, Wb_h1, nullptr, H8, N_NODES);
    agg_node<256, unsigned char, true, true, true, true><<<agg_grid, 256, 0, stream>>>(
        row_start, csr, dinv, H8, b_h1, nullptr, Xb);

    // ---- Layer 3: same ----
    gemm_mfma<256, 256, false, false, 2><<<gemm_grid, 256, 0, stream>>>(
        Xb, Wb_h2, nullptr, H8, N_NODES);
    agg_node<256, unsigned char, true, true, true, true><<<agg_grid, 256, 0, stream>>>(
        row_start, csr, dinv, H8, b_h2, nullptr, Xb);

    // ---- Layer 4: GEMM 256->128 (fp8 out), agg at 128 +bias -> fp32 ----
    gemm_mfma<256, 128, false, false, 2><<<gemm_grid, 256, 0, stream>>>(
        Xb, Wb_out, nullptr, H8_4, N_NODES);
    agg_node<128, unsigned char, true, false, false, false><<<agg_grid, 256, 0, stream>>>(
        row_start, csr, dinv, H8_4, b_out, A1, nullptr);

    // ---- readout: atomic-free per-graph mean (batch sorted) ----
    graph_mean<<<NGRAPH, 256, 0, stream>>>(bstart, A1, out);
}

// Round 21
// 380.713 us; speedup vs baseline: 1.5604x; 1.0393x over previous
//
#include <hip/hip_runtime.h>
#include <hip/hip_bf16.h>
#include <hip/hip_fp8.h>

#define N_NODES 50000
#define N_EDGES 800000
#define EMB_D 128
#define HID_D 256
#define OUT_D 128
#define NGRAPH 256

#define SCAN_B ((N_NODES + 256) / 256)   // 196 blocks covers N_NODES+1 slots
#define MAX_CSR (N_EDGES + 7 * N_NODES)  // pad-8 row capacity

typedef __attribute__((ext_vector_type(8))) short short8;
typedef __attribute__((ext_vector_type(4))) float floatx4;
typedef __attribute__((ext_vector_type(4))) unsigned short ushortx4;
typedef __attribute__((ext_vector_type(8))) unsigned short ushortx8;
typedef __attribute__((ext_vector_type(4))) unsigned char ucharx4;
typedef __attribute__((ext_vector_type(8))) unsigned char ucharx8;

__device__ inline unsigned short f2b(float f) {
    __hip_bfloat16 h = __float2bfloat16(f);
    return *reinterpret_cast<unsigned short*>(&h);
}

__device__ inline float b2f(unsigned short u) {
    union { unsigned int i; float f; } c;
    c.i = ((unsigned int)u) << 16;
    return c.f;
}

__device__ inline unsigned char f2f8(float f) {
    __hip_fp8_e4m3 v(f);                      // OCP e4m3 (gfx950 HW cvt)
    return (unsigned char)v.__x;
}

// message-operand element -> float (overloaded on storage type)
__device__ inline float h2f(unsigned short u) { return b2f(u); }
__device__ inline float h2f(unsigned char u) {
    __hip_fp8_e4m3 v; v.__x = (__hip_fp8_storage_t)u;
    return (float)v;
}

template<typename HT> struct UV8;
template<> struct UV8<unsigned short> { using T = ushortx8; };  // 16B/lane
template<> struct UV8<unsigned char>  { using T = ucharx8;  };  // 8B/lane

// ---------------- rank pass: 4-shard degree histogram + per-edge rank ----------------
__global__ void rank_kernel(const int* __restrict__ dst, int* __restrict__ deg4,
                            int* __restrict__ pos) {
    int e = blockIdx.x * blockDim.x + threadIdx.x;
    if (e >= N_EDGES) return;
    pos[e] = atomicAdd(&deg4[(size_t)(e & 3) * N_NODES + dst[e]], 1);
}

// ---------------- scan phase A: merge shards, block sums (PAD-8), dinv, shard bases ----
__global__ void scan_a(const int* __restrict__ deg4, int* __restrict__ degt,
                       int* __restrict__ degp, int* __restrict__ sb4,
                       int* __restrict__ bsum, float* __restrict__ dinv) {
    __shared__ int red[256];
    int t = threadIdx.x;
    int i = blockIdx.x * 256 + t;
    int pad = 0;
    if (i < N_NODES) {
        int d0 = deg4[i];
        int d1 = deg4[(size_t)N_NODES + i];
        int d2 = deg4[(size_t)2 * N_NODES + i];
        int d3 = deg4[(size_t)3 * N_NODES + i];
        int tot = d0 + d1 + d2 + d3;
        degt[i] = tot;
        pad = (tot + 7) & ~7;            // row padded to multiple of 8
        degp[i] = pad;
        dinv[i] = rsqrtf((float)tot + 1.0f);
        sb4[i] = 0;
        sb4[(size_t)N_NODES + i] = d0;
        sb4[(size_t)2 * N_NODES + i] = d0 + d1;
        sb4[(size_t)3 * N_NODES + i] = d0 + d1 + d2;
    }
    red[t] = pad;
    __syncthreads();
    for (int off = 128; off > 0; off >>= 1) {
        if (t < off) red[t] += red[t + off];
        __syncthreads();
    }
    if (t == 0) bsum[blockIdx.x] = red[0];
}

// ---------------- phase B: exclusive scan of block sums + graph boundaries (1 block) ----
__global__ void scan_b(const int* __restrict__ bsum, int* __restrict__ boff,
                       const int* __restrict__ batch, int* __restrict__ bstart) {
    int t = threadIdx.x;
    {
        int lo = 0, hi = N_NODES;
        while (lo < hi) {
            int mid = (lo + hi) >> 1;
            if (batch[mid] < t) lo = mid + 1;
            else hi = mid;
        }
        bstart[t] = lo;
        if (t == 0) bstart[NGRAPH] = N_NODES;
    }
    __shared__ int s[256];
    s[t] = (t < SCAN_B) ? bsum[t] : 0;
    __syncthreads();
    for (int off = 1; off < 256; off <<= 1) {
        int v = (t >= off) ? s[t - off] : 0;
        __syncthreads();
        s[t] += v;
        __syncthreads();
    }
    if (t < SCAN_B) boff[t] = (t == 0) ? 0 : s[t - 1];
}

// ---------------- phase C: in-block scan -> row_start (padded) + fused sentinel fill ----
__global__ void scan_c(const int* __restrict__ degp, const int* __restrict__ degt,
                       const int* __restrict__ boff, int* __restrict__ row_start,
                       unsigned int* __restrict__ csr) {
    __shared__ int s[256];
    int t = threadIdx.x;
    int i = blockIdx.x * 256 + t;
    int v = (i < N_NODES) ? degp[i] : 0;
    s[t] = v;
    __syncthreads();
    for (int off = 1; off < 256; off <<= 1) {
        int x = (t >= off) ? s[t - off] : 0;
        __syncthreads();
        s[t] += x;
        __syncthreads();
    }
    int excl = s[t] - v;
    int rs = boff[blockIdx.x] + excl;
    if (i <= N_NODES) row_start[i] = rs;
    if (i < N_NODES) {
        int e_true = rs + degt[i];
        int e_end  = rs + degp[i];
        for (int k = e_true; k < e_end; ++k) csr[k] = 0u;   // src=0, norm=0
    }
}

// ---------------- atomic-free CSR scatter (u16 src | bf16 norm packed in u32) ----------
__global__ void scatter_kernel(const int* __restrict__ src, const int* __restrict__ dst,
                               const int* __restrict__ pos, const int* __restrict__ row_start,
                               const int* __restrict__ sb4, const float* __restrict__ dinv,
                               unsigned int* __restrict__ csr) {
    int e = blockIdx.x * blockDim.x + threadIdx.x;
    if (e >= N_EDGES) return;
    int s = src[e], d = dst[e];
    int slot = row_start[d] + sb4[(size_t)(e & 3) * N_NODES + d] + pos[e];
    csr[slot] = ((unsigned int)f2b(dinv[s] * dinv[d]) << 16) | (unsigned int)s;
}

// ---------------- prep: embedding gather -> fp8 rows + W -> fragment-major bf16 --------
template<int K, int D>
__device__ inline void wsplit_one(int idx, const float* __restrict__ W,
                                  short* __restrict__ wb) {
    int j = idx & 7;
    int l = (idx >> 3) & 63;
    int rest = idx >> 9;
    int kb = rest % (K / 32);
    int t = rest / (K / 32);
    int k = kb * 32 + (l >> 4) * 8 + j;
    int ncol = t * 16 + (l & 15);
    wb[idx] = (short)f2b(W[(size_t)k * D + ncol]);
}

__global__ void prep_kernel(const int* __restrict__ ids, const float* __restrict__ embed,
                            unsigned char* __restrict__ E8,
                            const float* __restrict__ W_in, const float* __restrict__ W_h1,
                            const float* __restrict__ W_h2, const float* __restrict__ W_out,
                            short* __restrict__ wb_in, short* __restrict__ wb_h1,
                            short* __restrict__ wb_h2, short* __restrict__ wb_out) {
    int idx = blockIdx.x * blockDim.x + threadIdx.x;
    constexpr int GV = N_NODES * (EMB_D / 4);  // 1.6M float4->fp8x4 gathers
    if (idx < GV) {
        const int V = EMB_D / 4;
        int row = idx / V, c = idx % V;
        float4 v = ((const float4*)embed)[(size_t)ids[row] * V + c];
        ucharx4 u;
        u[0] = f2f8(v.x); u[1] = f2f8(v.y); u[2] = f2f8(v.z); u[3] = f2f8(v.w);
        ((ucharx4*)E8)[idx] = u;
        return;
    }
    int j = idx - GV;
    constexpr int S1 = EMB_D * HID_D;          // 32768
    constexpr int S2 = S1 + HID_D * HID_D;     // 98304
    constexpr int S3 = S2 + HID_D * HID_D;     // 163840
    constexpr int S4 = S3 + HID_D * OUT_D;     // 196608
    if (j < S1)      wsplit_one<EMB_D, HID_D>(j,      W_in,  wb_in);
    else if (j < S2) wsplit_one<HID_D, HID_D>(j - S1, W_h1,  wb_h1);
    else if (j < S3) wsplit_one<HID_D, HID_D>(j - S2, W_h2,  wb_h2);
    else if (j < S4) wsplit_one<HID_D, OUT_D>(j - S3, W_out, wb_out);
}

// ---------------- fused aggregation: 8 elems/lane, LPE lanes per edge -----------------
// D=256: 2 edge-groups/wave (32 lanes each, 16B/lane for bf16, 8B for fp8);
// D=128: 4 edge-groups/wave (16 lanes each, 8B/lane fp8) -> 2x fewer issues/edge.
// Rows padded to multiples of 8 (packed csr=0 sentinels) -> single uniform loop.
// BOUT: write result as single bf16 ROW-MAJOR plane; RES: residual from same plane.
template<int D, typename HT, bool HASB, bool RES, bool RELU, bool BOUT>
__global__ __launch_bounds__(256) void agg_node(
        const int* __restrict__ row_start, const unsigned int* __restrict__ csr,
        const float* __restrict__ dinv, const HT* __restrict__ H,
        const float* __restrict__ b, float* __restrict__ OUTF,
        unsigned short* __restrict__ Pb) {
    constexpr int LPE = (D == 128) ? 16 : 32;   // lanes per edge
    constexpr int NG  = 64 / LPE;               // edge groups per wave (2 or 4)
    constexpr int NP  = 8 / NG;                 // prefetched edges per group (4 or 2)
    using UV = typename UV8<HT>::T;
    using RV = ushortx8;
    int wave = threadIdx.x >> 6, lane = threadIdx.x & 63;
    int i = blockIdx.x * 4 + wave;
    if (i >= N_NODES) return;
    int grp = lane / LPE, gl = lane % LPE;
    const int off = gl * 8;
    const HT* __restrict__ Hoff = H + off;
    float acc0[8], acc1[8];
#pragma unroll
    for (int v = 0; v < 8; ++v) { acc0[v] = 0.f; acc1[v] = 0.f; }
    int e0 = row_start[i], e1 = row_start[i + 1];
    if (e0 < e1) {
        unsigned int sn[NP];
#pragma unroll
        for (int k = 0; k < NP; ++k) sn[k] = csr[e0 + k * NG + grp];
        int e = e0 + 8;
        for (;;) {
            UV u[NP];
            float nn[NP];
#pragma unroll
            for (int k = 0; k < NP; ++k) {
                u[k] = *(const UV*)(Hoff + (size_t)(sn[k] & 0xFFFFu) * D);
                nn[k] = b2f((unsigned short)(sn[k] >> 16));
            }
            bool more = (e < e1);
            unsigned int t[NP];
            if (more) {
#pragma unroll
                for (int k = 0; k < NP; ++k) t[k] = csr[e + k * NG + grp];
            }
#pragma unroll
            for (int k = 0; k < NP; ++k) {
                float* A = (k & 1) ? acc1 : acc0;
#pragma unroll
                for (int v = 0; v < 8; ++v) A[v] = fmaf(h2f(u[k][v]), nn[k], A[v]);
            }
            if (!more) break;
#pragma unroll
            for (int k = 0; k < NP; ++k) sn[k] = t[k];
            e += 8;
        }
    }
#pragma unroll
    for (int v = 0; v < 8; ++v) {
        float s = acc0[v] + acc1[v];
#pragma unroll
        for (int m = LPE; m < 64; m <<= 1) s += __shfl_xor(s, m);
        acc0[v] = s;
    }
    if (grp == 0) {
        float di = dinv[i];
        float d2 = di * di;
        UV us = *(const UV*)(Hoff + (size_t)i * D);
        RV rb;
        if (RES) rb = *(const RV*)(Pb + (size_t)i * D + off);
        RV ob;
#pragma unroll
        for (int v = 0; v < 8; ++v) {
            float val = acc0[v];
            val = fmaf(h2f(us[v]), d2, val);
            if (HASB) val += b[off + v];
            if (RES)  val += b2f(rb[v]);
            if (RELU) val = fmaxf(val, 0.f);
            if (BOUT) ob[v] = f2b(val);
            else      OUTF[(size_t)i * D + off + v] = val;
        }
        if (BOUT) *(RV*)(Pb + (size_t)i * D + off) = ob;
    }
}

// ---------------- MFMA GEMM: Hout[N,D] = A[N,K] @ W[K,D] (+bias)(+relu) ----------------
// Single-bf16 A (row-major plane) and W (fragment-major). ONE MFMA per tile per kb.
// OMODE: 0 = bf16 out, 2 = fp8 e4m3 out (message operand).
template<int K, int D, bool BIAS, bool RELU, int OMODE>
__global__ __launch_bounds__(256) void gemm_mfma(
        const unsigned short* __restrict__ A_g, const short* __restrict__ Wb,
        const float* __restrict__ b, void* __restrict__ OutB, int n) {
    constexpr int LDK = K + 8;
    constexpr int NT = D / 64;
    constexpr int KB = K / 32;
    __shared__ __align__(16) short Ab[64 * LDK];

    int row0 = blockIdx.x * 64;
    constexpr int NF8 = 64 * (K / 8);
    for (int idx = threadIdx.x; idx < NF8; idx += 256) {
        int r = idx / (K / 8), c8 = idx % (K / 8);
        ushortx8 vh = {0, 0, 0, 0, 0, 0, 0, 0};
        if (row0 + r < n)
            vh = *(const ushortx8*)(A_g + (size_t)(row0 + r) * K + c8 * 8);
        *(ushortx8*)&Ab[r * LDK + c8 * 8] = vh;
    }
    __syncthreads();

    int wave = threadIdx.x >> 6, lane = threadIdx.x & 63;
    int quad = lane >> 4, lane15 = lane & 15;

    floatx4 acc[4][NT];
#pragma unroll
    for (int mt = 0; mt < 4; ++mt)
#pragma unroll
        for (int nt = 0; nt < NT; ++nt)
            acc[mt][nt] = (floatx4){0.f, 0.f, 0.f, 0.f};

#pragma unroll
    for (int kb = 0; kb < KB; ++kb) {
        short8 ah[4];
#pragma unroll
        for (int mt = 0; mt < 4; ++mt) {
            int addr = (mt * 16 + lane15) * LDK + kb * 32 + quad * 8;
            ah[mt] = *(const short8*)&Ab[addr];
        }
        short8 bh[NT];
#pragma unroll
        for (int nt = 0; nt < NT; ++nt) {
            int t = wave * NT + nt;
            size_t fb = ((size_t)(t * KB + kb) * 64 + lane) * 8;
            bh[nt] = *(const short8*)&Wb[fb];
        }
#pragma unroll
        for (int mt = 0; mt < 4; ++mt)
#pragma unroll
            for (int nt = 0; nt < NT; ++nt)
                acc[mt][nt] = __builtin_amdgcn_mfma_f32_16x16x32_bf16(ah[mt], bh[nt], acc[mt][nt], 0, 0, 0);
    }

#pragma unroll
    for (int mt = 0; mt < 4; ++mt) {
#pragma unroll
        for (int nt = 0; nt < NT; ++nt) {
            int col = wave * (NT * 16) + nt * 16 + lane15;
            float bj = BIAS ? b[col] : 0.f;
#pragma unroll
            for (int reg = 0; reg < 4; ++reg) {
                int row = row0 + mt * 16 + quad * 4 + reg;
                if (row < n) {
                    float v = acc[mt][nt][reg] + bj;
                    if (RELU) v = fmaxf(v, 0.f);
                    if (OMODE == 2) ((unsigned char*)OutB)[(size_t)row * D + col] = f2f8(v);
                    else            ((unsigned short*)OutB)[(size_t)row * D + col] = f2b(v);
                }
            }
        }
    }
}

// ---------------- readout: one block per graph, atomic-free mean (bf16 in) -------------
__global__ void graph_mean(const int* __restrict__ bstart, const unsigned short* __restrict__ X,
                           float* __restrict__ out) {
    int g = blockIdx.x;
    int r0 = bstart[g], r1 = bstart[g + 1];
    int cp = threadIdx.x & 63, rr = threadIdx.x >> 6;  // 64 col-pairs, 4 rows in flight
    float a0 = 0.f, a1 = 0.f;
    for (int r = r0 + rr; r < r1; r += 4) {
        unsigned int w = ((const unsigned int*)X)[(size_t)r * 64 + cp];
        a0 += b2f((unsigned short)(w & 0xFFFFu));
        a1 += b2f((unsigned short)(w >> 16));
    }
    __shared__ float sh[2][3][64];
    if (rr > 0) { sh[0][rr - 1][cp] = a0; sh[1][rr - 1][cp] = a1; }
    __syncthreads();
    if (rr == 0) {
        float t0 = a0 + sh[0][0][cp] + sh[0][1][cp] + sh[0][2][cp];
        float t1 = a1 + sh[1][0][cp] + sh[1][1][cp] + sh[1][2][cp];
        int c = r1 - r0;
        float inv = 1.f / (float)(c > 0 ? c : 1);
        out[(size_t)g * OUT_D + cp * 2]     = t0 * inv;
        out[(size_t)g * OUT_D + cp * 2 + 1] = t1 * inv;
    }
}

extern "C" void kernel_launch(void* const* d_in, const int* in_sizes, int n_in,
                              void* d_out, int out_size, void* d_ws, size_t ws_size,
                              hipStream_t stream) {
    const int* node_ids = (const int*)d_in[0];
    const int* edge_index = (const int*)d_in[1];
    const int* batch = (const int*)d_in[2];
    const float* embed = (const float*)d_in[3];
    const float* W_in  = (const float*)d_in[4];
    const float* b_in  = (const float*)d_in[5];
    const float* W_h1  = (const float*)d_in[6];
    const float* b_h1  = (const float*)d_in[7];
    const float* W_h2  = (const float*)d_in[8];
    const float* b_h2  = (const float*)d_in[9];
    const float* W_out = (const float*)d_in[10];
    const float* b_out = (const float*)d_in[11];
    float* out = (float*)d_out;

    const int* src = edge_index;
    const int* dst = edge_index + N_EDGES;

    char* w = (char*)d_ws;
    size_t o = 0;
    auto alloc = [&](size_t bytes) -> void* {
        void* p = w + o;
        o = (o + bytes + 255) & ~(size_t)255;
        return p;
    };
    int*   deg4     = (int*)alloc((size_t)4 * N_NODES * sizeof(int));
    int*   sb4      = (int*)alloc((size_t)4 * N_NODES * sizeof(int));
    int*   degt     = (int*)alloc((size_t)N_NODES * sizeof(int));
    int*   degp     = (int*)alloc((size_t)N_NODES * sizeof(int));
    int*   pos      = (int*)alloc((size_t)N_EDGES * sizeof(int));
    float* dinv     = (float*)alloc((size_t)N_NODES * sizeof(float));
    int*   bstart   = (int*)alloc((size_t)(NGRAPH + 1) * sizeof(int));
    int*   row_start= (int*)alloc((size_t)(N_NODES + 1) * sizeof(int));
    int*   bsum     = (int*)alloc((size_t)SCAN_B * sizeof(int));
    int*   boff     = (int*)alloc((size_t)SCAN_B * sizeof(int));
    unsigned int* csr = (unsigned int*)alloc((size_t)MAX_CSR * sizeof(unsigned int));
    unsigned short* Xb  = (unsigned short*)alloc((size_t)N_NODES * HID_D * sizeof(short)); // bf16 X (residual + GEMM A)
    unsigned char*  E8  = (unsigned char*)alloc((size_t)N_NODES * EMB_D);                  // fp8 layer-1 operand
    unsigned char*  H8  = (unsigned char*)alloc((size_t)N_NODES * HID_D);                  // fp8 message operand (layers 2-4)
    unsigned short* A1b = (unsigned short*)alloc((size_t)N_NODES * 128 * sizeof(short));   // bf16 layer-1/-4 agg out
    short* Wb_in    = (short*)alloc((size_t)EMB_D * HID_D * sizeof(short));
    short* Wb_h1    = (short*)alloc((size_t)HID_D * HID_D * sizeof(short));
    short* Wb_h2    = (short*)alloc((size_t)HID_D * HID_D * sizeof(short));
    short* Wb_out   = (short*)alloc((size_t)HID_D * OUT_D * sizeof(short));
    unsigned char* H8_4 = H8;                // layer-4 fp8 GEMM out [N,128] alias
    (void)ws_size;

    hipMemsetAsync(deg4, 0, (size_t)4 * N_NODES * sizeof(int), stream);

    rank_kernel<<<(N_EDGES + 255) / 256, 256, 0, stream>>>(dst, deg4, pos);
    scan_a<<<SCAN_B, 256, 0, stream>>>(deg4, degt, degp, sb4, bsum, dinv);
    scan_b<<<1, 256, 0, stream>>>(bsum, boff, batch, bstart);   // + fused graph boundaries
    scan_c<<<SCAN_B, 256, 0, stream>>>(degp, degt, boff, row_start, csr);  // + fused pad fill
    scatter_kernel<<<(N_EDGES + 255) / 256, 256, 0, stream>>>(src, dst, pos, row_start,
                                                              sb4, dinv, csr);

    // fused: embedding gather (fp8) + all 4 weight repacks
    constexpr int GV = N_NODES * (EMB_D / 4);
    prep_kernel<<<(GV + 196608 + 255) / 256, 256, 0, stream>>>(
        node_ids, embed, E8, W_in, W_h1, W_h2, W_out, Wb_in, Wb_h1, Wb_h2, Wb_out);

    const int gemm_grid = (N_NODES + 63) / 64;
    const int agg_grid = (N_NODES + 3) / 4;

    // ---- Layer 1: agg fp8 emb at 128 (quarter-wave, bf16 out), GEMM 128->256 +b+relu ----
    agg_node<128, unsigned char, false, false, false, true><<<agg_grid, 256, 0, stream>>>(
        row_start, csr, dinv, E8, nullptr, nullptr, A1b);
    gemm_mfma<128, 256, true, true, 0><<<gemm_grid, 256, 0, stream>>>(
        A1b, Wb_in, b_in, Xb, N_NODES);

    // ---- Layer 2: GEMM 256->256 (fp8 out), fused agg+self+bias+residual+relu (bf16 out) ----
    gemm_mfma<256, 256, false, false, 2><<<gemm_grid, 256, 0, stream>>>(
        Xb, Wb_h1, nullptr, H8, N_NODES);
    agg_node<256, unsigned char, true, true, true, true><<<agg_grid, 256, 0, stream>>>(
        row_start, csr, dinv, H8, b_h1, nullptr, Xb);

    // ---- Layer 3: same ----
    gemm_mfma<256, 256, false, false, 2><<<gemm_grid, 256, 0, stream>>>(
        Xb, Wb_h2, nullptr, H8, N_NODES);
    agg_node<256, unsigned char, true, true, true, true><<<agg_grid, 256, 0, stream>>>(
        row_start, csr, dinv, H8, b_h2, nullptr, Xb);

    // ---- Layer 4: GEMM 256->128 (fp8 out), agg at 128 (quarter-wave) +bias -> bf16 ----
    gemm_mfma<256, 128, false, false, 2><<<gemm_grid, 256, 0, stream>>>(
        Xb, Wb_out, nullptr, H8_4, N_NODES);
    agg_node<128, unsigned char, true, false, false, true><<<agg_grid, 256, 0, stream>>>(
        row_start, csr, dinv, H8_4, b_out, nullptr, A1b);

    // ---- readout: atomic-free per-graph mean (batch sorted, bf16 in) ----
    graph_mean<<<NGRAPH, 256, 0, stream>>>(bstart, A1b, out);
}